// Round 1
// 655.049 us; speedup vs baseline: 1.0876x; 1.0876x over previous
//
#include <hip/hip_runtime.h>
#include <math.h>

typedef __attribute__((ext_vector_type(8))) short short8;
typedef __attribute__((ext_vector_type(4))) float floatx4;

__device__ __forceinline__ float b2f(ushort u) {
    union { uint i; float f; } c; c.i = ((uint)u) << 16; return c.f;
}
__device__ __forceinline__ ushort f2b(float f) {
    union { float f; uint i; } c; c.f = f;
    return (ushort)((c.i + 0x7fffu + ((c.i >> 16) & 1u)) >> 16);
}

__device__ __forceinline__ void async_cp16(const ushort* g, ushort* l) {
    __builtin_amdgcn_global_load_lds(
        (const __attribute__((address_space(1))) void*)g,
        (__attribute__((address_space(3))) void*)l, 16, 0, 0);
}

// max-reduce over the 16-lane DPP row using full-rate VALU DPP ops
__device__ __forceinline__ float dpp_max16(float x) {
    int y;
    y = __builtin_amdgcn_update_dpp(__float_as_int(x), __float_as_int(x), 0xB1, 0xF, 0xF, false);
    x = fmaxf(x, __int_as_float(y));
    y = __builtin_amdgcn_update_dpp(__float_as_int(x), __float_as_int(x), 0x4E, 0xF, 0xF, false);
    x = fmaxf(x, __int_as_float(y));
    y = __builtin_amdgcn_update_dpp(__float_as_int(x), __float_as_int(x), 0x141, 0xF, 0xF, false);
    x = fmaxf(x, __int_as_float(y));
    y = __builtin_amdgcn_update_dpp(__float_as_int(x), __float_as_int(x), 0x140, 0xF, 0xF, false);
    x = fmaxf(x, __int_as_float(y));
    return x;
}

// ---------------- fp32 [K,N] -> bf16 transposed [N,K] ----------------
__global__ __launch_bounds__(256) void cvt_t_kernel(
    const float* __restrict__ S, ushort* __restrict__ D, int K, int N)
{
    __shared__ float ls[32][33];
    const int k0 = blockIdx.y * 32, n0 = blockIdx.x * 32;
    const int t = threadIdx.x;
    const int kr = t >> 3, nc = (t & 7) * 4;
    float4 f = *(const float4*)(S + (size_t)(k0 + kr) * N + n0 + nc);
    ls[kr][nc] = f.x; ls[kr][nc + 1] = f.y; ls[kr][nc + 2] = f.z; ls[kr][nc + 3] = f.w;
    __syncthreads();
    const int nr = t >> 3, kc = (t & 7) * 4;
    ushort4 o;
    o.x = f2b(ls[kc][nr]); o.y = f2b(ls[kc + 1][nr]);
    o.z = f2b(ls[kc + 2][nr]); o.w = f2b(ls[kc + 3][nr]);
    *(ushort4*)(D + (size_t)(n0 + nr) * K + k0 + kc) = o;
}

// ---------------- LayerNorm: fp32 in, bf16 out ----------------
__global__ __launch_bounds__(256) void ln_kernel(
    const float* __restrict__ X, const float* __restrict__ G,
    const float* __restrict__ Bb, ushort* __restrict__ Y)
{
    const int row = blockIdx.x;
    const int t = threadIdx.x;
    const float* xr = X + (size_t)row * 1024;
    float4 p = ((const float4*)xr)[t];
    float s = p.x + p.y + p.z + p.w;
    float s2 = p.x * p.x + p.y * p.y + p.z * p.z + p.w * p.w;
    #pragma unroll
    for (int off = 32; off > 0; off >>= 1) {
        s += __shfl_down(s, off);
        s2 += __shfl_down(s2, off);
    }
    __shared__ float rs1[4], rs2[4];
    if ((t & 63) == 0) { rs1[t >> 6] = s; rs2[t >> 6] = s2; }
    __syncthreads();
    float S1 = rs1[0] + rs1[1] + rs1[2] + rs1[3];
    float S2 = rs2[0] + rs2[1] + rs2[2] + rs2[3];
    float mu = S1 * (1.0f / 1024.0f);
    float var = S2 * (1.0f / 1024.0f) - mu * mu;
    float rstd = rsqrtf(var + 1e-12f);
    float4 gp = ((const float4*)G)[t];
    float4 bp = ((const float4*)Bb)[t];
    ushort4 o;
    o.x = f2b((p.x - mu) * rstd * gp.x + bp.x);
    o.y = f2b((p.y - mu) * rstd * gp.y + bp.y);
    o.z = f2b((p.z - mu) * rstd * gp.z + bp.z);
    o.w = f2b((p.w - mu) * rstd * gp.w + bp.w);
    ((ushort4*)(Y + (size_t)row * 1024))[t] = o;
}

// ---------------- GEMM (B^T form, m97 structure): C[M,N] = A[M,K] @ Bt[N,K]^T
template<int BN, bool BIAS, bool SILU, bool RESID, bool OUTF32>
__global__ __launch_bounds__(256) void gemm_bt_kernel(
    const ushort* __restrict__ A, const ushort* __restrict__ Bt,
    const float* __restrict__ bias, const float* __restrict__ resid,
    void* __restrict__ Cm, int M, int N, int K)
{
    constexpr int NF = BN / 32;
    constexpr int BI = BN / 64;
    __shared__ __align__(16) ushort lsA[128 * 32];
    __shared__ __align__(16) ushort lsB[BN * 32];

    const int t = threadIdx.x;
    const int m0 = blockIdx.y * 128;
    const int n0 = blockIdx.x * BN;
    const int w = t >> 6;
    const int lane = t & 63;
    const int wm = (w >> 1) * 64;
    const int wn = (w & 1) * (BN / 2);
    const int quad = lane >> 4;
    const int l16 = lane & 15;
    const int ko = quad * 8;

    const int lrow = lane >> 2;
    const int scol = (lane & 3) * 8;
    const int srA = w * 32 + lrow;
    const int srB = (BI == 2) ? (w * 32 + lrow) : (w * 16 + lrow);
    const ushort* gA = A + (size_t)(m0 + srA) * K + scol;
    const ushort* gB = Bt + (size_t)(n0 + srB) * K + scol;
    ushort* lA0 = &lsA[(w * 32) * 32];
    ushort* lA1 = &lsA[(w * 32 + 16) * 32];
    ushort* lB0 = (BI == 2) ? &lsB[(w * 32) * 32] : &lsB[(w * 16) * 32];
    ushort* lB1 = (BI == 2) ? &lsB[(w * 32 + 16) * 32] : nullptr;

    floatx4 acc[4][NF];
    #pragma unroll
    for (int i = 0; i < 4; ++i)
        #pragma unroll
        for (int j = 0; j < NF; ++j)
            acc[i][j] = (floatx4){0.f, 0.f, 0.f, 0.f};

    for (int k0 = 0; k0 < K; k0 += 32) {
        __syncthreads();
        async_cp16(gA + k0, lA0);
        async_cp16(gA + (size_t)16 * K + k0, lA1);
        async_cp16(gB + k0, lB0);
        if constexpr (BI == 2) async_cp16(gB + (size_t)16 * K + k0, lB1);
        __syncthreads();

        short8 af[4], bf[NF];
        #pragma unroll
        for (int i = 0; i < 4; ++i)
            af[i] = *(const short8*)&lsA[(wm + i * 16 + l16) * 32 + ko];
        #pragma unroll
        for (int j = 0; j < NF; ++j)
            bf[j] = *(const short8*)&lsB[(wn + j * 16 + l16) * 32 + ko];
        #pragma unroll
        for (int i = 0; i < 4; ++i)
            #pragma unroll
            for (int j = 0; j < NF; ++j)
                acc[i][j] = __builtin_amdgcn_mfma_f32_16x16x32_bf16(
                    af[i], bf[j], acc[i][j], 0, 0, 0);
    }

    #pragma unroll
    for (int tn = 0; tn < NF; ++tn) {
        const int n = n0 + wn + tn * 16 + l16;
        const float bv = BIAS ? bias[n] : 0.0f;
        #pragma unroll
        for (int tm = 0; tm < 4; ++tm) {
            const int mbase = m0 + wm + tm * 16 + quad * 4;
            #pragma unroll
            for (int rr = 0; rr < 4; ++rr) {
                float v = acc[tm][tn][rr] + bv;
                if (SILU) v = v / (1.0f + __expf(-v));
                const size_t off = (size_t)(mbase + rr) * N + n;
                if (RESID) v += resid[off];
                if constexpr (OUTF32) ((float*)Cm)[off] = v;
                else                  ((ushort*)Cm)[off] = f2b(v);
            }
        }
    }
}

// ---------------- MFMA flash attention, paired q-tiles, 64 queries each ----
// grid (16, B*H), block 256 (4 waves). Each block processes q-tiles
// {31-pair, pair} -> (32-pair) + (pair+1) = 33 K-tiles per block, CONSTANT.
// 1024 uniform blocks = exactly 4 blocks/CU all-resident: no scheduling tail,
// 4 waves/SIMD of latency hiding (was time-avg 1.8 -> Occupancy 22.8%).
// P aliased onto Q's LDS (wave-private strips) -> 27.9 KB -> 4+ blocks/CU.
// K/V/mask prefetched into registers one tile ahead; softmax in exp2 domain;
// defer-max (THR=8): skip O/L rescale + al-exp2 when no row max grew >8.
__global__ __launch_bounds__(256, 4) void attn_kernel(
    const ushort* __restrict__ Qm, const ushort* __restrict__ Km,
    const ushort* __restrict__ Vm, const int* __restrict__ amask,
    ushort* __restrict__ Om, int rs)
{
    __shared__ __align__(16) ushort lsQP[64][72];  // Q staging, then P strips
    __shared__ __align__(16) ushort lsK[64][72];
    __shared__ __align__(16) ushort lsVt[64][72];  // [dim][key]
    __shared__ int lsMk[64];

    const int bh = blockIdx.y;
    const int b = bh >> 4, h = bh & 15;
    const int t = threadIdx.x;
    const int w = t >> 6, lane = t & 63;
    const int quad = lane >> 4, l16 = lane & 15;

    const size_t base = ((size_t)b * 2048) * rs + (size_t)h * 64;
    const size_t obase = ((size_t)b * 2048) * 1024 + (size_t)h * 64;

    const int krow = t >> 3, kc8 = (t & 7) << 3;   // K staging coords
    const int vp = t & 31, vc8 = (t >> 5) << 3;    // V staging coords
    const float scale2 = 0.125f * 1.44269504f;     // softmax in exp2 domain

    short8 ones8;
    #pragma unroll
    for (int i = 0; i < 8; ++i) ones8[i] = (short)0x3F80;  // bf16 1.0

    #pragma unroll 1
    for (int half = 0; half < 2; ++half) {
        const int qt = half ? blockIdx.x : (31 - blockIdx.x);
        const int q0 = qt * 64;

        __syncthreads();   // prior half's lsQP/lsK/lsVt reads complete
        // stage Q tile (64 x 64)
        #pragma unroll
        for (int it = 0; it < 2; ++it) {
            int idx = it * 256 + t;
            int row = idx >> 3, c8 = (idx & 7) << 3;
            *(int4*)&lsQP[row][c8] =
                *(const int4*)(Qm + base + (size_t)(q0 + row) * rs + c8);
        }
        __syncthreads();

        short8 aq0 = *(const short8*)&lsQP[w * 16 + l16][quad * 8];
        short8 aq1 = *(const short8*)&lsQP[w * 16 + l16][32 + quad * 8];

        floatx4 Oacc[4];
        #pragma unroll
        for (int d = 0; d < 4; ++d) Oacc[d] = (floatx4){0.f, 0.f, 0.f, 0.f};
        floatx4 Lacc = (floatx4){0.f, 0.f, 0.f, 0.f};
        float m_i[4] = {-INFINITY, -INFINITY, -INFINITY, -INFINITY};

        // prefetch tile 0
        int4 kr0 = *(const int4*)(Km + base + (size_t)krow * rs + kc8);
        int4 kr1 = *(const int4*)(Km + base + (size_t)(32 + krow) * rs + kc8);
        int4 vr0 = *(const int4*)(Vm + base + (size_t)(2 * vp) * rs + vc8);
        int4 vr1 = *(const int4*)(Vm + base + (size_t)(2 * vp + 1) * rs + vc8);
        int mr = amask[b * 2048 + (t & 63)];

        for (int kt = 0; kt <= qt; ++kt) {
            __syncthreads();   // previous tile's LDS reads complete
            *(int4*)&lsK[krow][kc8] = kr0;
            *(int4*)&lsK[32 + krow][kc8] = kr1;
            {
                const ushort* p0 = (const ushort*)&vr0;
                const ushort* p1 = (const ushort*)&vr1;
                #pragma unroll
                for (int i = 0; i < 8; ++i) {
                    uint pk = (uint)p0[i] | ((uint)p1[i] << 16);
                    *(uint*)&lsVt[vc8 + i][2 * vp] = pk;
                }
            }
            if (t < 64) lsMk[t] = mr;
            __syncthreads();   // tiles visible

            // prefetch next tile's K/V/mask into registers (overlaps compute)
            if (kt < qt) {
                const int kn = (kt + 1) * 64;
                kr0 = *(const int4*)(Km + base + (size_t)(kn + krow) * rs + kc8);
                kr1 = *(const int4*)(Km + base + (size_t)(kn + 32 + krow) * rs + kc8);
                vr0 = *(const int4*)(Vm + base + (size_t)(kn + 2 * vp) * rs + vc8);
                vr1 = *(const int4*)(Vm + base + (size_t)(kn + 2 * vp + 1) * rs + vc8);
                mr = amask[b * 2048 + kn + (t & 63)];
            }

            // ---- QK^T ----
            floatx4 sa[4];
            #pragma unroll
            for (int j = 0; j < 4; ++j) {
                short8 bk0 = *(const short8*)&lsK[j * 16 + l16][quad * 8];
                short8 bk1 = *(const short8*)&lsK[j * 16 + l16][32 + quad * 8];
                floatx4 z = (floatx4){0.f, 0.f, 0.f, 0.f};
                z = __builtin_amdgcn_mfma_f32_16x16x32_bf16(aq0, bk0, z, 0, 0, 0);
                sa[j] = __builtin_amdgcn_mfma_f32_16x16x32_bf16(aq1, bk1, z, 0, 0, 0);
            }

            float kb[4];
            #pragma unroll
            for (int j = 0; j < 4; ++j)
                kb[j] = (lsMk[j * 16 + l16] == 1) ? 0.f : -INFINITY;
            const bool diag = (kt == qt);

            // ---- online softmax (per C-layout row) ----
            float sv[4][4];
            float mx[4];
            #pragma unroll
            for (int rr = 0; rr < 4; ++rr) {
                const int qrow = w * 16 + quad * 4 + rr;
                float mxv = -INFINITY;
                #pragma unroll
                for (int j = 0; j < 4; ++j) {
                    float v = sa[j][rr] * scale2 + kb[j];
                    if (diag) v = (j * 16 + l16 <= qrow) ? v : -INFINITY;
                    sv[rr][j] = v;
                    mxv = fmaxf(mxv, v);
                }
                mx[rr] = dpp_max16(mxv);
            }
            // defer-max (T13): only rescale when some row's max grew past
            // m_i + 8 (exp2 domain). Otherwise keep old max; P bounded by 256.
            // First tile: m_i = -inf -> grow true -> normal path.
            int grow = (mx[0] > m_i[0] + 8.0f) | (mx[1] > m_i[1] + 8.0f) |
                       (mx[2] > m_i[2] + 8.0f) | (mx[3] > m_i[3] + 8.0f);
            if (__any(grow)) {
                #pragma unroll
                for (int rr = 0; rr < 4; ++rr) {
                    const float m_new = fmaxf(m_i[rr], mx[rr]);
                    const float al = exp2f(m_i[rr] - m_new);
                    m_i[rr] = m_new;
                    #pragma unroll
                    for (int d = 0; d < 4; ++d) Oacc[d][rr] *= al;
                    Lacc[rr] *= al;
                }
            }
            // P -> wave-private LDS strips (truncating bf16; L is computed
            // from the same truncated P via ones-MFMA so O/L stays exact)
            #pragma unroll
            for (int rr = 0; rr < 4; ++rr) {
                #pragma unroll
                for (int j = 0; j < 4; ++j) {
                    const float p = exp2f(sv[rr][j] - m_i[rr]);
                    lsQP[w * 16 + quad * 4 + rr][j * 16 + l16] =
                        (ushort)(__float_as_uint(p) >> 16);
                }
            }

            // ---- PV + L ----
            short8 ap0 = *(const short8*)&lsQP[w * 16 + l16][quad * 8];
            short8 ap1 = *(const short8*)&lsQP[w * 16 + l16][32 + quad * 8];
            #pragma unroll
            for (int d = 0; d < 4; ++d) {
                short8 bv0 = *(const short8*)&lsVt[d * 16 + l16][quad * 8];
                short8 bv1 = *(const short8*)&lsVt[d * 16 + l16][32 + quad * 8];
                Oacc[d] = __builtin_amdgcn_mfma_f32_16x16x32_bf16(ap0, bv0, Oacc[d], 0, 0, 0);
                Oacc[d] = __builtin_amdgcn_mfma_f32_16x16x32_bf16(ap1, bv1, Oacc[d], 0, 0, 0);
            }
            Lacc = __builtin_amdgcn_mfma_f32_16x16x32_bf16(ap0, ones8, Lacc, 0, 0, 0);
            Lacc = __builtin_amdgcn_mfma_f32_16x16x32_bf16(ap1, ones8, Lacc, 0, 0, 0);
        }

        #pragma unroll
        for (int rr = 0; rr < 4; ++rr) {
            const float inv = 1.0f / Lacc[rr];
            const int row = q0 + w * 16 + quad * 4 + rr;
            ushort* op = Om + obase + (size_t)row * 1024;
            #pragma unroll
            for (int d = 0; d < 4; ++d)
                op[d * 16 + l16] = f2b(Oacc[d][rr] * inv);
        }
    }
}

// ---------------- driver ----------------
// ws peak 72 MiB:
//   phase 1: xa [0,16) | qkvb [16,64) | Wqkv_t [64,70) | Wo_t [70,72)
//   phase 2: W1_t [0,8) W2_t [8,16) | yb [16,32) | hb chunk [32,64)
extern "C" void kernel_launch(void* const* d_in, const int* in_sizes, int n_in,
                              void* d_out, int out_size, void* d_ws, size_t ws_size,
                              hipStream_t stream) {
    const float* hidden = (const float*)d_in[0];
    const int*   amask  = (const int*)d_in[1];
    const float* Wq  = (const float*)d_in[2];
    const float* Wk  = (const float*)d_in[3];
    const float* Wv  = (const float*)d_in[4];
    const float* Wo  = (const float*)d_in[5];
    const float* l1g = (const float*)d_in[6];
    const float* l1b = (const float*)d_in[7];
    const float* W1  = (const float*)d_in[8];
    const float* b1  = (const float*)d_in[9];
    const float* W2  = (const float*)d_in[10];
    const float* b2  = (const float*)d_in[11];
    const float* l2g = (const float*)d_in[12];
    const float* l2b = (const float*)d_in[13];

    const int M = 8192;
    const size_t MB = 1048576;
    char* ws = (char*)d_ws;
    ushort* xa    = (ushort*)(ws);
    ushort* qkvb  = (ushort*)(ws + 16 * MB);
    ushort* Wqkvt = (ushort*)(ws + 64 * MB);
    ushort* Wot   = (ushort*)(ws + 70 * MB);
    ushort* W1t   = (ushort*)(ws);
    ushort* W2t   = (ushort*)(ws + 8 * MB);
    ushort* yb    = (ushort*)(ws + 16 * MB);
    ushort* hbc   = (ushort*)(ws + 32 * MB);
    float*  x2    = (float*)d_out;

    cvt_t_kernel<<<dim3(32, 32), 256, 0, stream>>>(Wq, Wqkvt, 1024, 1024);
    cvt_t_kernel<<<dim3(32, 32), 256, 0, stream>>>(Wk, Wqkvt + (size_t)1024 * 1024, 1024, 1024);
    cvt_t_kernel<<<dim3(32, 32), 256, 0, stream>>>(Wv, Wqkvt + (size_t)2048 * 1024, 1024, 1024);
    cvt_t_kernel<<<dim3(32, 32), 256, 0, stream>>>(Wo, Wot, 1024, 1024);

    ln_kernel<<<M, 256, 0, stream>>>(hidden, l1g, l1b, xa);
    gemm_bt_kernel<128, false, false, false, false><<<dim3(24, 64), 256, 0, stream>>>(
        xa, Wqkvt, nullptr, nullptr, qkvb, M, 3072, 1024);
    attn_kernel<<<dim3(16, 64), 256, 0, stream>>>(
        qkvb, qkvb + 1024, qkvb + 2048, amask, xa, 3072);
    gemm_bt_kernel<64, false, false, true, true><<<dim3(16, 64), 256, 0, stream>>>(
        xa, Wot, nullptr, hidden, x2, M, 1024, 1024);

    cvt_t_kernel<<<dim3(128, 32), 256, 0, stream>>>(W1, W1t, 1024, 4096);
    cvt_t_kernel<<<dim3(32, 128), 256, 0, stream>>>(W2, W2t, 4096, 1024);

    ln_kernel<<<M, 256, 0, stream>>>(x2, l2g, l2b, yb);
    for (int mc = 0; mc < 2; ++mc) {
        const size_t off = (size_t)mc * 4096 * 1024;
        gemm_bt_kernel<128, true, true, false, false><<<dim3(32, 32), 256, 0, stream>>>(
            yb + off, W1t, b1, nullptr, hbc, 4096, 4096, 1024);
        gemm_bt_kernel<64, true, false, true, true><<<dim3(16, 32), 256, 0, stream>>>(
            hbc, W2t, b2, x2 + off, (void*)(x2 + off), 4096, 1024, 4096);
    }
}

// Round 2
// 587.731 us; speedup vs baseline: 1.2122x; 1.1145x over previous
//
#include <hip/hip_runtime.h>
#include <math.h>

typedef __attribute__((ext_vector_type(8))) short short8;
typedef __attribute__((ext_vector_type(4))) float floatx4;
typedef __attribute__((ext_vector_type(2))) unsigned int uintx2;

__device__ __forceinline__ float b2f(ushort u) {
    union { uint i; float f; } c; c.i = ((uint)u) << 16; return c.f;
}
__device__ __forceinline__ ushort f2b(float f) {
    union { float f; uint i; } c; c.f = f;
    return (ushort)((c.i + 0x7fffu + ((c.i >> 16) & 1u)) >> 16);
}

__device__ __forceinline__ void async_cp16(const ushort* g, ushort* l) {
    __builtin_amdgcn_global_load_lds(
        (const __attribute__((address_space(1))) void*)g,
        (__attribute__((address_space(3))) void*)l, 16, 0, 0);
}

__device__ __forceinline__ uint lds_u32(const void* p) {
    return (uint)(uintptr_t)(const __attribute__((address_space(3))) void*)p;
}

// max-reduce over the 16-lane DPP row using full-rate VALU DPP ops
__device__ __forceinline__ float dpp_max16(float x) {
    int y;
    y = __builtin_amdgcn_update_dpp(__float_as_int(x), __float_as_int(x), 0xB1, 0xF, 0xF, false);
    x = fmaxf(x, __int_as_float(y));
    y = __builtin_amdgcn_update_dpp(__float_as_int(x), __float_as_int(x), 0x4E, 0xF, 0xF, false);
    x = fmaxf(x, __int_as_float(y));
    y = __builtin_amdgcn_update_dpp(__float_as_int(x), __float_as_int(x), 0x141, 0xF, 0xF, false);
    x = fmaxf(x, __int_as_float(y));
    y = __builtin_amdgcn_update_dpp(__float_as_int(x), __float_as_int(x), 0x140, 0xF, 0xF, false);
    x = fmaxf(x, __int_as_float(y));
    return x;
}

// ---------------- fp32 [K,N] -> bf16 transposed [N,K] ----------------
__global__ __launch_bounds__(256) void cvt_t_kernel(
    const float* __restrict__ S, ushort* __restrict__ D, int K, int N)
{
    __shared__ float ls[32][33];
    const int k0 = blockIdx.y * 32, n0 = blockIdx.x * 32;
    const int t = threadIdx.x;
    const int kr = t >> 3, nc = (t & 7) * 4;
    float4 f = *(const float4*)(S + (size_t)(k0 + kr) * N + n0 + nc);
    ls[kr][nc] = f.x; ls[kr][nc + 1] = f.y; ls[kr][nc + 2] = f.z; ls[kr][nc + 3] = f.w;
    __syncthreads();
    const int nr = t >> 3, kc = (t & 7) * 4;
    ushort4 o;
    o.x = f2b(ls[kc][nr]); o.y = f2b(ls[kc + 1][nr]);
    o.z = f2b(ls[kc + 2][nr]); o.w = f2b(ls[kc + 3][nr]);
    *(ushort4*)(D + (size_t)(n0 + nr) * K + k0 + kc) = o;
}

// ---------------- LayerNorm: fp32 in, bf16 out ----------------
__global__ __launch_bounds__(256) void ln_kernel(
    const float* __restrict__ X, const float* __restrict__ G,
    const float* __restrict__ Bb, ushort* __restrict__ Y)
{
    const int row = blockIdx.x;
    const int t = threadIdx.x;
    const float* xr = X + (size_t)row * 1024;
    float4 p = ((const float4*)xr)[t];
    float s = p.x + p.y + p.z + p.w;
    float s2 = p.x * p.x + p.y * p.y + p.z * p.z + p.w * p.w;
    #pragma unroll
    for (int off = 32; off > 0; off >>= 1) {
        s += __shfl_down(s, off);
        s2 += __shfl_down(s2, off);
    }
    __shared__ float rs1[4], rs2[4];
    if ((t & 63) == 0) { rs1[t >> 6] = s; rs2[t >> 6] = s2; }
    __syncthreads();
    float S1 = rs1[0] + rs1[1] + rs1[2] + rs1[3];
    float S2 = rs2[0] + rs2[1] + rs2[2] + rs2[3];
    float mu = S1 * (1.0f / 1024.0f);
    float var = S2 * (1.0f / 1024.0f) - mu * mu;
    float rstd = rsqrtf(var + 1e-12f);
    float4 gp = ((const float4*)G)[t];
    float4 bp = ((const float4*)Bb)[t];
    ushort4 o;
    o.x = f2b((p.x - mu) * rstd * gp.x + bp.x);
    o.y = f2b((p.y - mu) * rstd * gp.y + bp.y);
    o.z = f2b((p.z - mu) * rstd * gp.z + bp.z);
    o.w = f2b((p.w - mu) * rstd * gp.w + bp.w);
    ((ushort4*)(Y + (size_t)row * 1024))[t] = o;
}

// ---------------- GEMM (B^T form): C[M,N] = A[M,K] @ Bt[N,K]^T
// BK=64 (halved barrier/drain count vs BK=32). LDS rows are 128B -> XOR
// chunk-swizzle (chunk ^= row&7) keeps b128 frag reads at the optimal
// 8-cycle pattern. global_load_lds writes linearly, so the swizzle is
// applied by pre-swizzling the GLOBAL source column (rule 21).
// XCD-contiguous block remap: consecutive work ids land on one XCD.
template<int BN, bool BIAS, bool SILU, bool RESID, bool OUTF32>
__global__ __launch_bounds__(256) void gemm_bt_kernel(
    const ushort* __restrict__ A, const ushort* __restrict__ Bt,
    const float* __restrict__ bias, const float* __restrict__ resid,
    void* __restrict__ Cm, int M, int N, int K)
{
    constexpr int NF = BN / 32;
    constexpr int BI = BN / 64;
    __shared__ __align__(16) ushort lsA[128 * 64];
    __shared__ __align__(16) ushort lsB[BN * 64];

    const int t = threadIdx.x;
    const int L = blockIdx.x + gridDim.x * blockIdx.y;
    const int cpx = (gridDim.x * gridDim.y) >> 3;
    const int wg = (L & 7) * cpx + (L >> 3);
    const int m0 = (wg / gridDim.x) * 128;
    const int n0 = (wg % gridDim.x) * BN;
    const int w = t >> 6;
    const int lane = t & 63;
    const int wm = (w >> 1) * 64;
    const int wn = (w & 1) * (BN / 2);
    const int quad = lane >> 4;
    const int l16 = lane & 15;

    // staging: lane -> row = lane>>3 (8 rows/cp16), source k-chunk pre-swizzled
    const int lrow = lane >> 3;
    const int scol = ((lane & 7) ^ lrow) * 8;
    const ushort* gA = A + (size_t)(m0 + w * 32 + lrow) * K + scol;
    const ushort* gB = Bt + (size_t)(n0 + ((BI == 2) ? w * 32 : w * 16) + lrow) * K + scol;
    const int sw = l16 & 7;   // read-side XOR (row&7 == l16&7 for frag rows)

    floatx4 acc[4][NF];
    #pragma unroll
    for (int i = 0; i < 4; ++i)
        #pragma unroll
        for (int j = 0; j < NF; ++j)
            acc[i][j] = (floatx4){0.f, 0.f, 0.f, 0.f};

    for (int k0 = 0; k0 < K; k0 += 64) {
        __syncthreads();
        #pragma unroll
        for (int i = 0; i < 4; ++i)
            async_cp16(gA + k0 + (size_t)(8 * i) * K, &lsA[(w * 32 + 8 * i) * 64]);
        if constexpr (BI == 2) {
            #pragma unroll
            for (int i = 0; i < 4; ++i)
                async_cp16(gB + k0 + (size_t)(8 * i) * K, &lsB[(w * 32 + 8 * i) * 64]);
        } else {
            #pragma unroll
            for (int i = 0; i < 2; ++i)
                async_cp16(gB + k0 + (size_t)(8 * i) * K, &lsB[(w * 16 + 8 * i) * 64]);
        }
        __syncthreads();

        #pragma unroll
        for (int h = 0; h < 2; ++h) {
            const int co = (((h << 2) | quad) ^ sw) * 8;
            short8 af[4], bf[NF];
            #pragma unroll
            for (int i = 0; i < 4; ++i)
                af[i] = *(const short8*)&lsA[(wm + i * 16 + l16) * 64 + co];
            #pragma unroll
            for (int j = 0; j < NF; ++j)
                bf[j] = *(const short8*)&lsB[(wn + j * 16 + l16) * 64 + co];
            #pragma unroll
            for (int i = 0; i < 4; ++i)
                #pragma unroll
                for (int j = 0; j < NF; ++j)
                    acc[i][j] = __builtin_amdgcn_mfma_f32_16x16x32_bf16(
                        af[i], bf[j], acc[i][j], 0, 0, 0);
        }
    }

    #pragma unroll
    for (int tn = 0; tn < NF; ++tn) {
        const int n = n0 + wn + tn * 16 + l16;
        const float bv = BIAS ? bias[n] : 0.0f;
        #pragma unroll
        for (int tm = 0; tm < 4; ++tm) {
            const int mbase = m0 + wm + tm * 16 + quad * 4;
            #pragma unroll
            for (int rr = 0; rr < 4; ++rr) {
                float v = acc[tm][tn][rr] + bv;
                if (SILU) v = v / (1.0f + __expf(-v));
                const size_t off = (size_t)(mbase + rr) * N + n;
                if (RESID) v += resid[off];
                if constexpr (OUTF32) ((float*)Cm)[off] = v;
                else                  ((ushort*)Cm)[off] = f2b(v);
            }
        }
    }
}

// ---------------- MFMA flash attention, paired q-tiles, 64 queries each ----
// grid (16, B*H), block 256 (4 waves). Block L: bh = L&63, pair = L>>6 so the
// 16 blocks sharing one (b,h)'s K/V sit on ONE XCD (L mod 8 == bh mod 8);
// 8 bh x 512KB K/V = 4MB = one L2. Work per block = 33 K-tiles, constant.
// Softmax: lazy row-max (local max + __any for the grow test; dpp reduce only
// inside the rare rescale branch). P round-trip: cvt_pk pairs -> PT strip
// [64k][16q] (4x ds_write_b64) -> A-frags via 4x ds_read_b64_tr_b16.
__global__ __launch_bounds__(256, 4) void attn_kernel(
    const ushort* __restrict__ Qm, const ushort* __restrict__ Km,
    const ushort* __restrict__ Vm, const int* __restrict__ amask,
    ushort* __restrict__ Om, int rs)
{
    __shared__ __align__(16) ushort lsQP[64][72];  // Q staging, then PT strips
    __shared__ __align__(16) ushort lsK[64][72];
    __shared__ __align__(16) ushort lsVt[64][72];  // [dim][key]
    __shared__ int lsMk[64];

    const int L = blockIdx.x + (int)(gridDim.x * blockIdx.y);
    const int bh = L & 63;
    const int pr = L >> 6;                 // 0..15
    const int b = bh >> 4, h = bh & 15;
    const int t = threadIdx.x;
    const int w = t >> 6, lane = t & 63;
    const int quad = lane >> 4, l16 = lane & 15;

    const size_t base = ((size_t)b * 2048) * rs + (size_t)h * 64;
    const size_t obase = ((size_t)b * 2048) * 1024 + (size_t)h * 64;

    const int krow = t >> 3, kc8 = (t & 7) << 3;   // K staging coords
    const int vp = t & 31, vc8 = (t >> 5) << 3;    // V staging coords
    const float scale2 = 0.125f * 1.44269504f;     // softmax in exp2 domain

    // PT strip (wave-private, aliases this wave's 16 Q rows = 2304B >= 2048B)
    ushort* strip = &lsQP[w * 16][0];
    const uint strip_a = lds_u32(strip);
    char* wp_base = (char*)strip + l16 * 32 + quad * 8;   // PT write addr
    const uint rp = strip_a + quad * 256 + l16 * 8;       // tr-read addr

    short8 ones8;
    #pragma unroll
    for (int i = 0; i < 8; ++i) ones8[i] = (short)0x3F80;  // bf16 1.0

    #pragma unroll 1
    for (int half = 0; half < 2; ++half) {
        const int qt = half ? pr : (31 - pr);
        const int q0 = qt * 64;

        __syncthreads();   // prior half's LDS reads complete
        // stage Q tile (64 x 64)
        #pragma unroll
        for (int it = 0; it < 2; ++it) {
            int idx = it * 256 + t;
            int row = idx >> 3, c8 = (idx & 7) << 3;
            *(int4*)&lsQP[row][c8] =
                *(const int4*)(Qm + base + (size_t)(q0 + row) * rs + c8);
        }
        __syncthreads();

        short8 aq0 = *(const short8*)&lsQP[w * 16 + l16][quad * 8];
        short8 aq1 = *(const short8*)&lsQP[w * 16 + l16][32 + quad * 8];

        floatx4 Oacc[4];
        #pragma unroll
        for (int d = 0; d < 4; ++d) Oacc[d] = (floatx4){0.f, 0.f, 0.f, 0.f};
        floatx4 Lacc = (floatx4){0.f, 0.f, 0.f, 0.f};
        float m_i[4] = {-INFINITY, -INFINITY, -INFINITY, -INFINITY};

        // prefetch tile 0
        int4 kr0 = *(const int4*)(Km + base + (size_t)krow * rs + kc8);
        int4 kr1 = *(const int4*)(Km + base + (size_t)(32 + krow) * rs + kc8);
        int4 vr0 = *(const int4*)(Vm + base + (size_t)(2 * vp) * rs + vc8);
        int4 vr1 = *(const int4*)(Vm + base + (size_t)(2 * vp + 1) * rs + vc8);
        int mr = amask[b * 2048 + (t & 63)];

        for (int kt = 0; kt <= qt; ++kt) {
            __syncthreads();   // previous tile's LDS reads complete
            *(int4*)&lsK[krow][kc8] = kr0;
            *(int4*)&lsK[32 + krow][kc8] = kr1;
            {
                const ushort* p0 = (const ushort*)&vr0;
                const ushort* p1 = (const ushort*)&vr1;
                #pragma unroll
                for (int i = 0; i < 8; ++i) {
                    uint pk = (uint)p0[i] | ((uint)p1[i] << 16);
                    *(uint*)&lsVt[vc8 + i][2 * vp] = pk;
                }
            }
            if (t < 64) lsMk[t] = mr;
            __syncthreads();   // tiles visible

            // prefetch next tile's K/V/mask into registers (overlaps compute)
            if (kt < qt) {
                const int kn = (kt + 1) * 64;
                kr0 = *(const int4*)(Km + base + (size_t)(kn + krow) * rs + kc8);
                kr1 = *(const int4*)(Km + base + (size_t)(kn + 32 + krow) * rs + kc8);
                vr0 = *(const int4*)(Vm + base + (size_t)(kn + 2 * vp) * rs + vc8);
                vr1 = *(const int4*)(Vm + base + (size_t)(kn + 2 * vp + 1) * rs + vc8);
                mr = amask[b * 2048 + kn + (t & 63)];
            }

            // ---- QK^T ----
            floatx4 sa[4];
            #pragma unroll
            for (int j = 0; j < 4; ++j) {
                short8 bk0 = *(const short8*)&lsK[j * 16 + l16][quad * 8];
                short8 bk1 = *(const short8*)&lsK[j * 16 + l16][32 + quad * 8];
                floatx4 z = (floatx4){0.f, 0.f, 0.f, 0.f};
                z = __builtin_amdgcn_mfma_f32_16x16x32_bf16(aq0, bk0, z, 0, 0, 0);
                sa[j] = __builtin_amdgcn_mfma_f32_16x16x32_bf16(aq1, bk1, z, 0, 0, 0);
            }

            float kb[4];
            #pragma unroll
            for (int j = 0; j < 4; ++j)
                kb[j] = (lsMk[j * 16 + l16] == 1) ? 0.f : -INFINITY;
            const bool diag = (kt == qt);

            // ---- online softmax: lazy row-max ----
            float sv[4][4];
            float mxl[4];
            #pragma unroll
            for (int rr = 0; rr < 4; ++rr) {
                const int qrow = w * 16 + quad * 4 + rr;
                float mxv = -INFINITY;
                #pragma unroll
                for (int j = 0; j < 4; ++j) {
                    float v = sa[j][rr] * scale2 + kb[j];
                    if (diag) v = (j * 16 + l16 <= qrow) ? v : -INFINITY;
                    sv[rr][j] = v;
                    mxv = fmaxf(mxv, v);
                }
                mxl[rr] = mxv;
            }
            // grow test on LOCAL maxes; __any gives the row-wide OR for free.
            // grow=false  =>  every lane's max <= m_i+8  =>  row max <= m_i+8
            // => P bounded by 2^8 (bf16/f32 accum tolerates). Same semantics
            // as full defer-max, minus 32 dpp-chain ops in the common path.
            int grow = (mxl[0] > m_i[0] + 8.0f) | (mxl[1] > m_i[1] + 8.0f) |
                       (mxl[2] > m_i[2] + 8.0f) | (mxl[3] > m_i[3] + 8.0f);
            if (__any(grow)) {
                #pragma unroll
                for (int rr = 0; rr < 4; ++rr) {
                    const float mx = dpp_max16(mxl[rr]);
                    const float m_new = fmaxf(m_i[rr], mx);
                    const float al = exp2f(m_i[rr] - m_new);
                    m_i[rr] = m_new;
                    #pragma unroll
                    for (int d = 0; d < 4; ++d) Oacc[d][rr] *= al;
                    Lacc[rr] *= al;
                }
            }

            // ---- P -> PT strip [64 k][16 q]: cvt_pk pairs + 4x b64 writes ----
            #pragma unroll
            for (int j = 0; j < 4; ++j) {
                float p0 = exp2f(sv[0][j] - m_i[0]);
                float p1 = exp2f(sv[1][j] - m_i[1]);
                float p2 = exp2f(sv[2][j] - m_i[2]);
                float p3 = exp2f(sv[3][j] - m_i[3]);
                uint w0, w1;
                asm("v_cvt_pk_bf16_f32 %0, %1, %2" : "=v"(w0) : "v"(p0), "v"(p1));
                asm("v_cvt_pk_bf16_f32 %0, %1, %2" : "=v"(w1) : "v"(p2), "v"(p3));
                *(uint2*)(wp_base + j * 512) = make_uint2(w0, w1);
            }

            // ---- PT -> A-frags via hardware transpose reads ----
            asm volatile("s_waitcnt lgkmcnt(0)" ::: "memory");
            uintx2 t0, t1, t2, t3;
            asm volatile("ds_read_b64_tr_b16 %0, %1 offset:0"    : "=v"(t0) : "v"(rp));
            asm volatile("ds_read_b64_tr_b16 %0, %1 offset:128"  : "=v"(t1) : "v"(rp));
            asm volatile("ds_read_b64_tr_b16 %0, %1 offset:1024" : "=v"(t2) : "v"(rp));
            asm volatile("ds_read_b64_tr_b16 %0, %1 offset:1152" : "=v"(t3) : "v"(rp));
            asm volatile("s_waitcnt lgkmcnt(0)" ::: "memory");
            __builtin_amdgcn_sched_barrier(0);
            union { short8 s; uint u[4]; } ua0, ua1;
            ua0.u[0] = t0.x; ua0.u[1] = t0.y; ua0.u[2] = t1.x; ua0.u[3] = t1.y;
            ua1.u[0] = t2.x; ua1.u[1] = t2.y; ua1.u[2] = t3.x; ua1.u[3] = t3.y;
            const short8 ap0 = ua0.s;
            const short8 ap1 = ua1.s;

            // ---- PV + L ----
            #pragma unroll
            for (int d = 0; d < 4; ++d) {
                short8 bv0 = *(const short8*)&lsVt[d * 16 + l16][quad * 8];
                short8 bv1 = *(const short8*)&lsVt[d * 16 + l16][32 + quad * 8];
                Oacc[d] = __builtin_amdgcn_mfma_f32_16x16x32_bf16(ap0, bv0, Oacc[d], 0, 0, 0);
                Oacc[d] = __builtin_amdgcn_mfma_f32_16x16x32_bf16(ap1, bv1, Oacc[d], 0, 0, 0);
            }
            Lacc = __builtin_amdgcn_mfma_f32_16x16x32_bf16(ap0, ones8, Lacc, 0, 0, 0);
            Lacc = __builtin_amdgcn_mfma_f32_16x16x32_bf16(ap1, ones8, Lacc, 0, 0, 0);
        }

        #pragma unroll
        for (int rr = 0; rr < 4; ++rr) {
            const float inv = 1.0f / Lacc[rr];
            const int row = q0 + w * 16 + quad * 4 + rr;
            ushort* op = Om + obase + (size_t)row * 1024;
            #pragma unroll
            for (int d = 0; d < 4; ++d)
                op[d * 16 + l16] = f2b(Oacc[d][rr] * inv);
        }
    }
}

// ---------------- driver ----------------
// ws peak 72 MiB:
//   phase 1: xa [0,16) | qkvb [16,64) | Wqkv_t [64,70) | Wo_t [70,72)
//   phase 2: W1_t [0,8) W2_t [8,16) | yb [16,32) | hb chunk [32,64)
extern "C" void kernel_launch(void* const* d_in, const int* in_sizes, int n_in,
                              void* d_out, int out_size, void* d_ws, size_t ws_size,
                              hipStream_t stream) {
    const float* hidden = (const float*)d_in[0];
    const int*   amask  = (const int*)d_in[1];
    const float* Wq  = (const float*)d_in[2];
    const float* Wk  = (const float*)d_in[3];
    const float* Wv  = (const float*)d_in[4];
    const float* Wo  = (const float*)d_in[5];
    const float* l1g = (const float*)d_in[6];
    const float* l1b = (const float*)d_in[7];
    const float* W1  = (const float*)d_in[8];
    const float* b1  = (const float*)d_in[9];
    const float* W2  = (const float*)d_in[10];
    const float* b2  = (const float*)d_in[11];
    const float* l2g = (const float*)d_in[12];
    const float* l2b = (const float*)d_in[13];

    const int M = 8192;
    const size_t MB = 1048576;
    char* ws = (char*)d_ws;
    ushort* xa    = (ushort*)(ws);
    ushort* qkvb  = (ushort*)(ws + 16 * MB);
    ushort* Wqkvt = (ushort*)(ws + 64 * MB);
    ushort* Wot   = (ushort*)(ws + 70 * MB);
    ushort* W1t   = (ushort*)(ws);
    ushort* W2t   = (ushort*)(ws + 8 * MB);
    ushort* yb    = (ushort*)(ws + 16 * MB);
    ushort* hbc   = (ushort*)(ws + 32 * MB);
    float*  x2    = (float*)d_out;

    cvt_t_kernel<<<dim3(32, 32), 256, 0, stream>>>(Wq, Wqkvt, 1024, 1024);
    cvt_t_kernel<<<dim3(32, 32), 256, 0, stream>>>(Wk, Wqkvt + (size_t)1024 * 1024, 1024, 1024);
    cvt_t_kernel<<<dim3(32, 32), 256, 0, stream>>>(Wv, Wqkvt + (size_t)2048 * 1024, 1024, 1024);
    cvt_t_kernel<<<dim3(32, 32), 256, 0, stream>>>(Wo, Wot, 1024, 1024);

    ln_kernel<<<M, 256, 0, stream>>>(hidden, l1g, l1b, xa);
    gemm_bt_kernel<128, false, false, false, false><<<dim3(24, 64), 256, 0, stream>>>(
        xa, Wqkvt, nullptr, nullptr, qkvb, M, 3072, 1024);
    attn_kernel<<<dim3(16, 64), 256, 0, stream>>>(
        qkvb, qkvb + 1024, qkvb + 2048, amask, xa, 3072);
    gemm_bt_kernel<64, false, false, true, true><<<dim3(16, 64), 256, 0, stream>>>(
        xa, Wot, nullptr, hidden, x2, M, 1024, 1024);

    cvt_t_kernel<<<dim3(128, 32), 256, 0, stream>>>(W1, W1t, 1024, 4096);
    cvt_t_kernel<<<dim3(32, 128), 256, 0, stream>>>(W2, W2t, 4096, 1024);

    ln_kernel<<<M, 256, 0, stream>>>(x2, l2g, l2b, yb);
    for (int mc = 0; mc < 2; ++mc) {
        const size_t off = (size_t)mc * 4096 * 1024;
        gemm_bt_kernel<128, true, true, false, false><<<dim3(32, 32), 256, 0, stream>>>(
            yb + off, W1t, b1, nullptr, hbc, 4096, 4096, 1024);
        gemm_bt_kernel<64, true, false, true, true><<<dim3(16, 32), 256, 0, stream>>>(
            hbc, W2t, b2, x2 + off, (void*)(x2 + off), 4096, 1024, 4096);
    }
}

// Round 3
// 573.568 us; speedup vs baseline: 1.2421x; 1.0247x over previous
//
#include <hip/hip_runtime.h>
#include <math.h>

typedef __attribute__((ext_vector_type(8))) short short8;
typedef __attribute__((ext_vector_type(4))) float floatx4;
typedef __attribute__((ext_vector_type(2))) unsigned int uintx2;

__device__ __forceinline__ float b2f(ushort u) {
    union { uint i; float f; } c; c.i = ((uint)u) << 16; return c.f;
}
__device__ __forceinline__ ushort f2b(float f) {
    union { float f; uint i; } c; c.f = f;
    return (ushort)((c.i + 0x7fffu + ((c.i >> 16) & 1u)) >> 16);
}

__device__ __forceinline__ void async_cp16(const ushort* g, ushort* l) {
    __builtin_amdgcn_global_load_lds(
        (const __attribute__((address_space(1))) void*)g,
        (__attribute__((address_space(3))) void*)l, 16, 0, 0);
}

__device__ __forceinline__ uint lds_u32(const void* p) {
    return (uint)(uintptr_t)(const __attribute__((address_space(3))) void*)p;
}

// max-reduce over the 16-lane DPP row using full-rate VALU DPP ops
__device__ __forceinline__ float dpp_max16(float x) {
    int y;
    y = __builtin_amdgcn_update_dpp(__float_as_int(x), __float_as_int(x), 0xB1, 0xF, 0xF, false);
    x = fmaxf(x, __int_as_float(y));
    y = __builtin_amdgcn_update_dpp(__float_as_int(x), __float_as_int(x), 0x4E, 0xF, 0xF, false);
    x = fmaxf(x, __int_as_float(y));
    y = __builtin_amdgcn_update_dpp(__float_as_int(x), __float_as_int(x), 0x141, 0xF, 0xF, false);
    x = fmaxf(x, __int_as_float(y));
    y = __builtin_amdgcn_update_dpp(__float_as_int(x), __float_as_int(x), 0x140, 0xF, 0xF, false);
    x = fmaxf(x, __int_as_float(y));
    return x;
}

// ---------------- fp32 [K,N] -> bf16 transposed [N,K] ----------------
__global__ __launch_bounds__(256) void cvt_t_kernel(
    const float* __restrict__ S, ushort* __restrict__ D, int K, int N)
{
    __shared__ float ls[32][33];
    const int k0 = blockIdx.y * 32, n0 = blockIdx.x * 32;
    const int t = threadIdx.x;
    const int kr = t >> 3, nc = (t & 7) * 4;
    float4 f = *(const float4*)(S + (size_t)(k0 + kr) * N + n0 + nc);
    ls[kr][nc] = f.x; ls[kr][nc + 1] = f.y; ls[kr][nc + 2] = f.z; ls[kr][nc + 3] = f.w;
    __syncthreads();
    const int nr = t >> 3, kc = (t & 7) * 4;
    ushort4 o;
    o.x = f2b(ls[kc][nr]); o.y = f2b(ls[kc + 1][nr]);
    o.z = f2b(ls[kc + 2][nr]); o.w = f2b(ls[kc + 3][nr]);
    *(ushort4*)(D + (size_t)(n0 + nr) * K + k0 + kc) = o;
}

// ---------------- LayerNorm: fp32 in, bf16 out ----------------
__global__ __launch_bounds__(256) void ln_kernel(
    const float* __restrict__ X, const float* __restrict__ G,
    const float* __restrict__ Bb, ushort* __restrict__ Y)
{
    const int row = blockIdx.x;
    const int t = threadIdx.x;
    const float* xr = X + (size_t)row * 1024;
    float4 p = ((const float4*)xr)[t];
    float s = p.x + p.y + p.z + p.w;
    float s2 = p.x * p.x + p.y * p.y + p.z * p.z + p.w * p.w;
    #pragma unroll
    for (int off = 32; off > 0; off >>= 1) {
        s += __shfl_down(s, off);
        s2 += __shfl_down(s2, off);
    }
    __shared__ float rs1[4], rs2[4];
    if ((t & 63) == 0) { rs1[t >> 6] = s; rs2[t >> 6] = s2; }
    __syncthreads();
    float S1 = rs1[0] + rs1[1] + rs1[2] + rs1[3];
    float S2 = rs2[0] + rs2[1] + rs2[2] + rs2[3];
    float mu = S1 * (1.0f / 1024.0f);
    float var = S2 * (1.0f / 1024.0f) - mu * mu;
    float rstd = rsqrtf(var + 1e-12f);
    float4 gp = ((const float4*)G)[t];
    float4 bp = ((const float4*)Bb)[t];
    ushort4 o;
    o.x = f2b((p.x - mu) * rstd * gp.x + bp.x);
    o.y = f2b((p.y - mu) * rstd * gp.y + bp.y);
    o.z = f2b((p.z - mu) * rstd * gp.z + bp.z);
    o.w = f2b((p.w - mu) * rstd * gp.w + bp.w);
    ((ushort4*)(Y + (size_t)row * 1024))[t] = o;
}

// ---------------- GEMM (B^T form): C[M,N] = A[M,K] @ Bt[N,K]^T
// BK=64, XOR chunk-swizzle applied via pre-swizzled GLOBAL source (rule 21),
// XCD-contiguous block remap.
template<int BN, bool BIAS, bool SILU, bool RESID, bool OUTF32>
__global__ __launch_bounds__(256) void gemm_bt_kernel(
    const ushort* __restrict__ A, const ushort* __restrict__ Bt,
    const float* __restrict__ bias, const float* __restrict__ resid,
    void* __restrict__ Cm, int M, int N, int K)
{
    constexpr int NF = BN / 32;
    constexpr int BI = BN / 64;
    __shared__ __align__(16) ushort lsA[128 * 64];
    __shared__ __align__(16) ushort lsB[BN * 64];

    const int t = threadIdx.x;
    const int L = blockIdx.x + gridDim.x * blockIdx.y;
    const int cpx = (gridDim.x * gridDim.y) >> 3;
    const int wg = (L & 7) * cpx + (L >> 3);
    const int m0 = (wg / gridDim.x) * 128;
    const int n0 = (wg % gridDim.x) * BN;
    const int w = t >> 6;
    const int lane = t & 63;
    const int wm = (w >> 1) * 64;
    const int wn = (w & 1) * (BN / 2);
    const int quad = lane >> 4;
    const int l16 = lane & 15;

    const int lrow = lane >> 3;
    const int scol = ((lane & 7) ^ lrow) * 8;
    const ushort* gA = A + (size_t)(m0 + w * 32 + lrow) * K + scol;
    const ushort* gB = Bt + (size_t)(n0 + ((BI == 2) ? w * 32 : w * 16) + lrow) * K + scol;
    const int sw = l16 & 7;

    floatx4 acc[4][NF];
    #pragma unroll
    for (int i = 0; i < 4; ++i)
        #pragma unroll
        for (int j = 0; j < NF; ++j)
            acc[i][j] = (floatx4){0.f, 0.f, 0.f, 0.f};

    for (int k0 = 0; k0 < K; k0 += 64) {
        __syncthreads();
        #pragma unroll
        for (int i = 0; i < 4; ++i)
            async_cp16(gA + k0 + (size_t)(8 * i) * K, &lsA[(w * 32 + 8 * i) * 64]);
        if constexpr (BI == 2) {
            #pragma unroll
            for (int i = 0; i < 4; ++i)
                async_cp16(gB + k0 + (size_t)(8 * i) * K, &lsB[(w * 32 + 8 * i) * 64]);
        } else {
            #pragma unroll
            for (int i = 0; i < 2; ++i)
                async_cp16(gB + k0 + (size_t)(8 * i) * K, &lsB[(w * 16 + 8 * i) * 64]);
        }
        __syncthreads();

        #pragma unroll
        for (int h = 0; h < 2; ++h) {
            const int co = (((h << 2) | quad) ^ sw) * 8;
            short8 af[4], bf[NF];
            #pragma unroll
            for (int i = 0; i < 4; ++i)
                af[i] = *(const short8*)&lsA[(wm + i * 16 + l16) * 64 + co];
            #pragma unroll
            for (int j = 0; j < NF; ++j)
                bf[j] = *(const short8*)&lsB[(wn + j * 16 + l16) * 64 + co];
            #pragma unroll
            for (int i = 0; i < 4; ++i)
                #pragma unroll
                for (int j = 0; j < NF; ++j)
                    acc[i][j] = __builtin_amdgcn_mfma_f32_16x16x32_bf16(
                        af[i], bf[j], acc[i][j], 0, 0, 0);
        }
    }

    #pragma unroll
    for (int tn = 0; tn < NF; ++tn) {
        const int n = n0 + wn + tn * 16 + l16;
        const float bv = BIAS ? bias[n] : 0.0f;
        #pragma unroll
        for (int tm = 0; tm < 4; ++tm) {
            const int mbase = m0 + wm + tm * 16 + quad * 4;
            #pragma unroll
            for (int rr = 0; rr < 4; ++rr) {
                float v = acc[tm][tn][rr] + bv;
                if (SILU) v = v / (1.0f + __expf(-v));
                const size_t off = (size_t)(mbase + rr) * N + n;
                if (RESID) v += resid[off];
                if constexpr (OUTF32) ((float*)Cm)[off] = v;
                else                  ((ushort*)Cm)[off] = f2b(v);
            }
        }
    }
}

// ---------------- MFMA flash attention, paired q-tiles, 64 queries each ----
// grid (16, B*H), block 256 (4 waves). Block L: bh = L&63 so the 16 blocks
// sharing one (b,h)'s K/V sit on ONE XCD. 33 K-tiles/block, constant.
// V path: async global_load_lds into subtiled [kgrp][dgrp][4][16] layout
// (addr = base + 16*lane, exactly linear), double-buffered; B-frags read with
// ds_read_b64_tr_b16 (conflict-free 128B subtile per 16-lane group). DMA for
// tile t+1 is issued right after barrier-2 of tile t; the compiler's
// vmcnt(0)-before-barrier drains it at tile t+1's first barrier — a full
// tile of compute hides the latency.
// P round-trip: cvt_pk -> PT strip [64k][16q] -> 4x ds_read_b64_tr_b16.
// Softmax: lazy row-max + defer-max (THR=8, exp2 domain).
__global__ __launch_bounds__(256, 4) void attn_kernel(
    const ushort* __restrict__ Qm, const ushort* __restrict__ Km,
    const ushort* __restrict__ Vm, const int* __restrict__ amask,
    ushort* __restrict__ Om, int rs)
{
    __shared__ __align__(16) ushort lsQP[64][72];   // Q staging, then PT strips
    __shared__ __align__(16) ushort lsK[64][72];
    __shared__ __align__(16) ushort lsV2[2][4096];  // subtiled V, double-buffered
    __shared__ int lsMk[64];

    const int L = blockIdx.x + (int)(gridDim.x * blockIdx.y);
    const int bh = L & 63;
    const int pr = L >> 6;                 // 0..15
    const int b = bh >> 4, h = bh & 15;
    const int t = threadIdx.x;
    const int w = t >> 6, lane = t & 63;
    const int quad = lane >> 4, l16 = lane & 15;

    const size_t base = ((size_t)b * 2048) * rs + (size_t)h * 64;
    const size_t obase = ((size_t)b * 2048) * 1024 + (size_t)h * 64;

    const int krow = t >> 3, kc8 = (t & 7) << 3;   // K staging coords
    const float scale2 = 0.125f * 1.44269504f;     // softmax in exp2 domain

    // V DMA lane mapping: k-offset and d-column such that the subtiled LDS
    // address (kg*512 + dgrp*128 + krow*32 + dhalf*16 bytes) == base + 16*lane.
    const int vkofs = ((lane >> 5) << 2) + ((lane >> 1) & 3);
    const int vdofs = ((lane >> 3) & 3) * 16 + (lane & 1) * 8;

    // PT strip (wave-private, aliases this wave's 16 Q rows)
    ushort* strip = &lsQP[w * 16][0];
    const uint strip_a = lds_u32(strip);
    char* wp_base = (char*)strip + l16 * 32 + quad * 8;   // PT write addr
    const uint rp = strip_a + quad * 256 + l16 * 8;       // PT tr-read addr

    short8 ones8;
    #pragma unroll
    for (int i = 0; i < 8; ++i) ones8[i] = (short)0x3F80;  // bf16 1.0

    #pragma unroll 1
    for (int half = 0; half < 2; ++half) {
        const int qt = half ? pr : (31 - pr);
        const int q0 = qt * 64;

        __syncthreads();   // prior half's LDS reads complete

        // V DMA for tile 0 (lands by the post-Q-stage barrier's drain)
        async_cp16(Vm + base + (size_t)(16 * w + vkofs) * rs + vdofs,
                   &lsV2[0][(4 * w) * 256]);
        async_cp16(Vm + base + (size_t)(16 * w + 8 + vkofs) * rs + vdofs,
                   &lsV2[0][(4 * w + 2) * 256]);

        // stage Q tile (64 x 64)
        #pragma unroll
        for (int it = 0; it < 2; ++it) {
            int idx = it * 256 + t;
            int row = idx >> 3, c8 = (idx & 7) << 3;
            *(int4*)&lsQP[row][c8] =
                *(const int4*)(Qm + base + (size_t)(q0 + row) * rs + c8);
        }
        __syncthreads();

        short8 aq0 = *(const short8*)&lsQP[w * 16 + l16][quad * 8];
        short8 aq1 = *(const short8*)&lsQP[w * 16 + l16][32 + quad * 8];

        floatx4 Oacc[4];
        #pragma unroll
        for (int d = 0; d < 4; ++d) Oacc[d] = (floatx4){0.f, 0.f, 0.f, 0.f};
        floatx4 Lacc = (floatx4){0.f, 0.f, 0.f, 0.f};
        float m_i[4] = {-INFINITY, -INFINITY, -INFINITY, -INFINITY};

        // prefetch tile 0 K/mask into registers
        int4 kr0 = *(const int4*)(Km + base + (size_t)krow * rs + kc8);
        int4 kr1 = *(const int4*)(Km + base + (size_t)(32 + krow) * rs + kc8);
        int mr = amask[b * 2048 + (t & 63)];

        for (int kt = 0; kt <= qt; ++kt) {
            __syncthreads();   // previous tile's LDS reads complete;
                               // compiler vmcnt(0) drain => V(kt) has landed
            *(int4*)&lsK[krow][kc8] = kr0;
            *(int4*)&lsK[32 + krow][kc8] = kr1;
            if (t < 64) lsMk[t] = mr;
            __syncthreads();   // tiles visible

            // prefetch next tile: K/mask into regs, V via async DMA
            if (kt < qt) {
                const int kn = (kt + 1) * 64;
                kr0 = *(const int4*)(Km + base + (size_t)(kn + krow) * rs + kc8);
                kr1 = *(const int4*)(Km + base + (size_t)(kn + 32 + krow) * rs + kc8);
                mr = amask[b * 2048 + kn + (t & 63)];
                ushort* vd = &lsV2[(kt + 1) & 1][0];
                async_cp16(Vm + base + (size_t)(kn + 16 * w + vkofs) * rs + vdofs,
                           vd + (4 * w) * 256);
                async_cp16(Vm + base + (size_t)(kn + 16 * w + 8 + vkofs) * rs + vdofs,
                           vd + (4 * w + 2) * 256);
            }

            // ---- QK^T ----
            floatx4 sa[4];
            #pragma unroll
            for (int j = 0; j < 4; ++j) {
                short8 bk0 = *(const short8*)&lsK[j * 16 + l16][quad * 8];
                short8 bk1 = *(const short8*)&lsK[j * 16 + l16][32 + quad * 8];
                floatx4 z = (floatx4){0.f, 0.f, 0.f, 0.f};
                z = __builtin_amdgcn_mfma_f32_16x16x32_bf16(aq0, bk0, z, 0, 0, 0);
                sa[j] = __builtin_amdgcn_mfma_f32_16x16x32_bf16(aq1, bk1, z, 0, 0, 0);
            }

            float kb[4];
            #pragma unroll
            for (int j = 0; j < 4; ++j)
                kb[j] = (lsMk[j * 16 + l16] == 1) ? 0.f : -INFINITY;
            const bool diag = (kt == qt);

            // ---- online softmax: lazy row-max ----
            float sv[4][4];
            float mxl[4];
            #pragma unroll
            for (int rr = 0; rr < 4; ++rr) {
                const int qrow = w * 16 + quad * 4 + rr;
                float mxv = -INFINITY;
                #pragma unroll
                for (int j = 0; j < 4; ++j) {
                    float v = sa[j][rr] * scale2 + kb[j];
                    if (diag) v = (j * 16 + l16 <= qrow) ? v : -INFINITY;
                    sv[rr][j] = v;
                    mxv = fmaxf(mxv, v);
                }
                mxl[rr] = mxv;
            }
            int grow = (mxl[0] > m_i[0] + 8.0f) | (mxl[1] > m_i[1] + 8.0f) |
                       (mxl[2] > m_i[2] + 8.0f) | (mxl[3] > m_i[3] + 8.0f);
            if (__any(grow)) {
                #pragma unroll
                for (int rr = 0; rr < 4; ++rr) {
                    const float mx = dpp_max16(mxl[rr]);
                    const float m_new = fmaxf(m_i[rr], mx);
                    const float al = exp2f(m_i[rr] - m_new);
                    m_i[rr] = m_new;
                    #pragma unroll
                    for (int d = 0; d < 4; ++d) Oacc[d][rr] *= al;
                    Lacc[rr] *= al;
                }
            }

            // ---- P -> PT strip [64 k][16 q]: cvt_pk pairs + 4x b64 writes ----
            #pragma unroll
            for (int j = 0; j < 4; ++j) {
                float p0 = exp2f(sv[0][j] - m_i[0]);
                float p1 = exp2f(sv[1][j] - m_i[1]);
                float p2 = exp2f(sv[2][j] - m_i[2]);
                float p3 = exp2f(sv[3][j] - m_i[3]);
                uint w0, w1;
                asm("v_cvt_pk_bf16_f32 %0, %1, %2" : "=v"(w0) : "v"(p0), "v"(p1));
                asm("v_cvt_pk_bf16_f32 %0, %1, %2" : "=v"(w1) : "v"(p2), "v"(p3));
                *(uint2*)(wp_base + j * 512) = make_uint2(w0, w1);
            }

            // ---- PT -> A-frags via hardware transpose reads ----
            asm volatile("s_waitcnt lgkmcnt(0)" ::: "memory");
            uintx2 t0, t1, t2, t3;
            asm volatile("ds_read_b64_tr_b16 %0, %1 offset:0"    : "=v"(t0) : "v"(rp));
            asm volatile("ds_read_b64_tr_b16 %0, %1 offset:128"  : "=v"(t1) : "v"(rp));
            asm volatile("ds_read_b64_tr_b16 %0, %1 offset:1024" : "=v"(t2) : "v"(rp));
            asm volatile("ds_read_b64_tr_b16 %0, %1 offset:1152" : "=v"(t3) : "v"(rp));
            asm volatile("s_waitcnt lgkmcnt(0)" ::: "memory");
            __builtin_amdgcn_sched_barrier(0);
            union { short8 s; uint u[4]; } ua0, ua1;
            ua0.u[0] = t0.x; ua0.u[1] = t0.y; ua0.u[2] = t1.x; ua0.u[3] = t1.y;
            ua1.u[0] = t2.x; ua1.u[1] = t2.y; ua1.u[2] = t3.x; ua1.u[3] = t3.y;
            const short8 ap0 = ua0.s;
            const short8 ap1 = ua1.s;

            // ---- PV + L: V B-frags via transpose reads from subtiled LDS ----
            const uint vb = lds_u32(&lsV2[kt & 1][0]) + quad * 1024 + l16 * 8;
            #pragma unroll
            for (int db = 0; db < 4; ++db) {
                const uint vbd = vb + db * 128;
                uintx2 v0, v1, v2, v3;
                asm volatile("ds_read_b64_tr_b16 %0, %1 offset:0"    : "=v"(v0) : "v"(vbd));
                asm volatile("ds_read_b64_tr_b16 %0, %1 offset:512"  : "=v"(v1) : "v"(vbd));
                asm volatile("ds_read_b64_tr_b16 %0, %1 offset:4096" : "=v"(v2) : "v"(vbd));
                asm volatile("ds_read_b64_tr_b16 %0, %1 offset:4608" : "=v"(v3) : "v"(vbd));
                asm volatile("s_waitcnt lgkmcnt(0)" ::: "memory");
                __builtin_amdgcn_sched_barrier(0);
                union { short8 s; uint u[4]; } ub0, ub1;
                ub0.u[0] = v0.x; ub0.u[1] = v0.y; ub0.u[2] = v1.x; ub0.u[3] = v1.y;
                ub1.u[0] = v2.x; ub1.u[1] = v2.y; ub1.u[2] = v3.x; ub1.u[3] = v3.y;
                Oacc[db] = __builtin_amdgcn_mfma_f32_16x16x32_bf16(ap0, ub0.s, Oacc[db], 0, 0, 0);
                Oacc[db] = __builtin_amdgcn_mfma_f32_16x16x32_bf16(ap1, ub1.s, Oacc[db], 0, 0, 0);
            }
            Lacc = __builtin_amdgcn_mfma_f32_16x16x32_bf16(ap0, ones8, Lacc, 0, 0, 0);
            Lacc = __builtin_amdgcn_mfma_f32_16x16x32_bf16(ap1, ones8, Lacc, 0, 0, 0);
        }

        #pragma unroll
        for (int rr = 0; rr < 4; ++rr) {
            const float inv = 1.0f / Lacc[rr];
            const int row = q0 + w * 16 + quad * 4 + rr;
            ushort* op = Om + obase + (size_t)row * 1024;
            #pragma unroll
            for (int d = 0; d < 4; ++d)
                op[d * 16 + l16] = f2b(Oacc[d][rr] * inv);
        }
    }
}

// ---------------- driver ----------------
// ws peak 72 MiB:
//   phase 1: xa [0,16) | qkvb [16,64) | Wqkv_t [64,70) | Wo_t [70,72)
//   phase 2: W1_t [0,8) W2_t [8,16) | yb [16,32) | hb chunk [32,64)
extern "C" void kernel_launch(void* const* d_in, const int* in_sizes, int n_in,
                              void* d_out, int out_size, void* d_ws, size_t ws_size,
                              hipStream_t stream) {
    const float* hidden = (const float*)d_in[0];
    const int*   amask  = (const int*)d_in[1];
    const float* Wq  = (const float*)d_in[2];
    const float* Wk  = (const float*)d_in[3];
    const float* Wv  = (const float*)d_in[4];
    const float* Wo  = (const float*)d_in[5];
    const float* l1g = (const float*)d_in[6];
    const float* l1b = (const float*)d_in[7];
    const float* W1  = (const float*)d_in[8];
    const float* b1  = (const float*)d_in[9];
    const float* W2  = (const float*)d_in[10];
    const float* b2  = (const float*)d_in[11];
    const float* l2g = (const float*)d_in[12];
    const float* l2b = (const float*)d_in[13];

    const int M = 8192;
    const size_t MB = 1048576;
    char* ws = (char*)d_ws;
    ushort* xa    = (ushort*)(ws);
    ushort* qkvb  = (ushort*)(ws + 16 * MB);
    ushort* Wqkvt = (ushort*)(ws + 64 * MB);
    ushort* Wot   = (ushort*)(ws + 70 * MB);
    ushort* W1t   = (ushort*)(ws);
    ushort* W2t   = (ushort*)(ws + 8 * MB);
    ushort* yb    = (ushort*)(ws + 16 * MB);
    ushort* hbc   = (ushort*)(ws + 32 * MB);
    float*  x2    = (float*)d_out;

    cvt_t_kernel<<<dim3(32, 32), 256, 0, stream>>>(Wq, Wqkvt, 1024, 1024);
    cvt_t_kernel<<<dim3(32, 32), 256, 0, stream>>>(Wk, Wqkvt + (size_t)1024 * 1024, 1024, 1024);
    cvt_t_kernel<<<dim3(32, 32), 256, 0, stream>>>(Wv, Wqkvt + (size_t)2048 * 1024, 1024, 1024);
    cvt_t_kernel<<<dim3(32, 32), 256, 0, stream>>>(Wo, Wot, 1024, 1024);

    ln_kernel<<<M, 256, 0, stream>>>(hidden, l1g, l1b, xa);
    gemm_bt_kernel<128, false, false, false, false><<<dim3(24, 64), 256, 0, stream>>>(
        xa, Wqkvt, nullptr, nullptr, qkvb, M, 3072, 1024);
    attn_kernel<<<dim3(16, 64), 256, 0, stream>>>(
        qkvb, qkvb + 1024, qkvb + 2048, amask, xa, 3072);
    gemm_bt_kernel<64, false, false, true, true><<<dim3(16, 64), 256, 0, stream>>>(
        xa, Wot, nullptr, hidden, x2, M, 1024, 1024);

    cvt_t_kernel<<<dim3(128, 32), 256, 0, stream>>>(W1, W1t, 1024, 4096);
    cvt_t_kernel<<<dim3(32, 128), 256, 0, stream>>>(W2, W2t, 4096, 1024);

    ln_kernel<<<M, 256, 0, stream>>>(x2, l2g, l2b, yb);
    for (int mc = 0; mc < 2; ++mc) {
        const size_t off = (size_t)mc * 4096 * 1024;
        gemm_bt_kernel<128, true, true, false, false><<<dim3(32, 32), 256, 0, stream>>>(
            yb + off, W1t, b1, nullptr, hbc, 4096, 4096, 1024);
        gemm_bt_kernel<64, true, false, true, true><<<dim3(16, 32), 256, 0, stream>>>(
            hbc, W2t, b2, x2 + off, (void*)(x2 + off), 4096, 1024, 4096);
    }
}

// Round 4
// 562.986 us; speedup vs baseline: 1.2655x; 1.0188x over previous
//
#include <hip/hip_runtime.h>
#include <math.h>

typedef __attribute__((ext_vector_type(8))) short short8;
typedef __attribute__((ext_vector_type(4))) float floatx4;
typedef __attribute__((ext_vector_type(2))) unsigned int uintx2;

__device__ __forceinline__ float b2f(ushort u) {
    union { uint i; float f; } c; c.i = ((uint)u) << 16; return c.f;
}
__device__ __forceinline__ ushort f2b(float f) {
    union { float f; uint i; } c; c.f = f;
    return (ushort)((c.i + 0x7fffu + ((c.i >> 16) & 1u)) >> 16);
}

__device__ __forceinline__ void async_cp16(const ushort* g, ushort* l) {
    __builtin_amdgcn_global_load_lds(
        (const __attribute__((address_space(1))) void*)g,
        (__attribute__((address_space(3))) void*)l, 16, 0, 0);
}

__device__ __forceinline__ uint lds_u32(const void* p) {
    return (uint)(uintptr_t)(const __attribute__((address_space(3))) void*)p;
}

// max-reduce over the 16-lane DPP row using full-rate VALU DPP ops
__device__ __forceinline__ float dpp_max16(float x) {
    int y;
    y = __builtin_amdgcn_update_dpp(__float_as_int(x), __float_as_int(x), 0xB1, 0xF, 0xF, false);
    x = fmaxf(x, __int_as_float(y));
    y = __builtin_amdgcn_update_dpp(__float_as_int(x), __float_as_int(x), 0x4E, 0xF, 0xF, false);
    x = fmaxf(x, __int_as_float(y));
    y = __builtin_amdgcn_update_dpp(__float_as_int(x), __float_as_int(x), 0x141, 0xF, 0xF, false);
    x = fmaxf(x, __int_as_float(y));
    y = __builtin_amdgcn_update_dpp(__float_as_int(x), __float_as_int(x), 0x140, 0xF, 0xF, false);
    x = fmaxf(x, __int_as_float(y));
    return x;
}

// ---------------- fp32 [K,N] -> bf16 transposed [N,K] ----------------
__global__ __launch_bounds__(256) void cvt_t_kernel(
    const float* __restrict__ S, ushort* __restrict__ D, int K, int N)
{
    __shared__ float ls[32][33];
    const int k0 = blockIdx.y * 32, n0 = blockIdx.x * 32;
    const int t = threadIdx.x;
    const int kr = t >> 3, nc = (t & 7) * 4;
    float4 f = *(const float4*)(S + (size_t)(k0 + kr) * N + n0 + nc);
    ls[kr][nc] = f.x; ls[kr][nc + 1] = f.y; ls[kr][nc + 2] = f.z; ls[kr][nc + 3] = f.w;
    __syncthreads();
    const int nr = t >> 3, kc = (t & 7) * 4;
    ushort4 o;
    o.x = f2b(ls[kc][nr]); o.y = f2b(ls[kc + 1][nr]);
    o.z = f2b(ls[kc + 2][nr]); o.w = f2b(ls[kc + 3][nr]);
    *(ushort4*)(D + (size_t)(n0 + nr) * K + k0 + kc) = o;
}

// ---------------- LayerNorm: fp32 in, bf16 out ----------------
__global__ __launch_bounds__(256) void ln_kernel(
    const float* __restrict__ X, const float* __restrict__ G,
    const float* __restrict__ Bb, ushort* __restrict__ Y)
{
    const int row = blockIdx.x;
    const int t = threadIdx.x;
    const float* xr = X + (size_t)row * 1024;
    float4 p = ((const float4*)xr)[t];
    float s = p.x + p.y + p.z + p.w;
    float s2 = p.x * p.x + p.y * p.y + p.z * p.z + p.w * p.w;
    #pragma unroll
    for (int off = 32; off > 0; off >>= 1) {
        s += __shfl_down(s, off);
        s2 += __shfl_down(s2, off);
    }
    __shared__ float rs1[4], rs2[4];
    if ((t & 63) == 0) { rs1[t >> 6] = s; rs2[t >> 6] = s2; }
    __syncthreads();
    float S1 = rs1[0] + rs1[1] + rs1[2] + rs1[3];
    float S2 = rs2[0] + rs2[1] + rs2[2] + rs2[3];
    float mu = S1 * (1.0f / 1024.0f);
    float var = S2 * (1.0f / 1024.0f) - mu * mu;
    float rstd = rsqrtf(var + 1e-12f);
    float4 gp = ((const float4*)G)[t];
    float4 bp = ((const float4*)Bb)[t];
    ushort4 o;
    o.x = f2b((p.x - mu) * rstd * gp.x + bp.x);
    o.y = f2b((p.y - mu) * rstd * gp.y + bp.y);
    o.z = f2b((p.z - mu) * rstd * gp.z + bp.z);
    o.w = f2b((p.w - mu) * rstd * gp.w + bp.w);
    ((ushort4*)(Y + (size_t)row * 1024))[t] = o;
}

// ---------------- 256x256 8-phase GEMM (T2+T3+T4+T5): C = A @ Bt^T ----------
// 512 threads (8 waves, 2M x 4N), BK=64, LDS [2buf][A/B][ks][256][32] = 128KB.
// Staging: K-column halves (16KB, 2 x global_load_lds rounds, linear dest);
// chunk-XOR swizzle (chunk ^= row&3) via pre-swizzled GLOBAL source + same
// XOR on ds_read (rule 21) -> frag reads 2-way = free.
// Schedule per K-tile kt (4 phases of 16 MFMA):
//   p0: vmcnt(8)+s_barrier; stage Ha1(kt+1); read B[ks0],A[ks0,mh0]; MFMA
//   p1:                     stage Hb1(kt+1); read A[ks0,mh1];        MFMA
//   p2: vmcnt(8)+s_barrier; stage Ha0(kt+2); read B[ks1],A[ks1,mh0]; MFMA
//   p3:                     stage Hb0(kt+2); read A[ks1,mh1];        MFMA
// Steady state: 12 loads in flight before each wait, trimmed to 8 (4 halves).
// Liveness (verified): every region overwritten >=2 phases after last read,
// protected by the even-phase barrier. Tail: waits peel 8 -> 4 -> 0.
template<bool BIAS, bool SILU>
__global__ __launch_bounds__(512, 2) void gemm256_kernel(
    const ushort* __restrict__ A, const ushort* __restrict__ Bt,
    const float* __restrict__ bias, ushort* __restrict__ Cm,
    int M, int N, int K)
{
    __shared__ __align__(16) ushort lds[2][2][2][256][32];

    const int t = threadIdx.x;
    const int L = blockIdx.x + (int)(gridDim.x * blockIdx.y);
    const int cpx = (int)(gridDim.x * gridDim.y) >> 3;
    const int wg = (L & 7) * cpx + (L >> 3);
    const int m0 = (wg / gridDim.x) * 256;
    const int n0 = (wg % gridDim.x) * 256;
    const int w = t >> 6, lane = t & 63;
    const int wr = w >> 2, wc = w & 3;
    const int quad = lane >> 4, l16 = lane & 15;

    // staging lane map: row = w*16 + (lane>>2) (+128 for round 1),
    // phys chunk = lane&3; source chunk pre-swizzled by row&3
    const int srow = lane >> 2;
    const int schunk = ((lane & 3) ^ (srow & 3)) * 8;
    const ushort* gA = A + (size_t)(m0 + w * 16 + srow) * K + schunk;
    const ushort* gB = Bt + (size_t)(n0 + w * 16 + srow) * K + schunk;
    const int NT = K >> 6;

    // frag-read phys chunk: logical chunk quad, row&3 == l16&3
    const int pch = (quad ^ (l16 & 3)) * 8;

    floatx4 acc[8][4];
    #pragma unroll
    for (int i = 0; i < 8; ++i)
        #pragma unroll
        for (int j = 0; j < 4; ++j)
            acc[i][j] = (floatx4){0.f, 0.f, 0.f, 0.f};

    auto STAGE = [&](int bb, int mat, int ks, int kt) {
        const ushort* g = (mat ? gB : gA) + (size_t)kt * 64 + ks * 32;
        ushort* l0 = &lds[bb][mat][ks][w * 16][0];
        async_cp16(g, l0);
        async_cp16(g + (size_t)128 * K, l0 + 128 * 32);
    };

    // prologue: Ha0(0) Hb0(0) Ha1(0) Hb1(0) Ha0(1) Hb0(1) -> 12 loads in flight
    STAGE(0, 0, 0, 0); STAGE(0, 1, 0, 0);
    STAGE(0, 0, 1, 0); STAGE(0, 1, 1, 0);
    STAGE(1, 0, 0, 1); STAGE(1, 1, 0, 1);

    #pragma unroll 1
    for (int kt = 0; kt < NT; ++kt) {
        const int bb = kt & 1;
        short8 bf[4];

        // ---- p0 ----
        if (kt < NT - 1) asm volatile("s_waitcnt vmcnt(8)" ::: "memory");
        else             asm volatile("s_waitcnt vmcnt(4)" ::: "memory");
        __builtin_amdgcn_s_barrier();
        __builtin_amdgcn_sched_barrier(0);
        if (kt + 1 < NT) STAGE(bb ^ 1, 0, 1, kt + 1);
        #pragma unroll
        for (int nj = 0; nj < 4; ++nj)
            bf[nj] = *(const short8*)&lds[bb][1][0][wc * 64 + nj * 16 + l16][pch];
        {
            short8 af[4];
            #pragma unroll
            for (int mi = 0; mi < 4; ++mi)
                af[mi] = *(const short8*)&lds[bb][0][0][wr * 128 + mi * 16 + l16][pch];
            __builtin_amdgcn_s_setprio(1);
            #pragma unroll
            for (int mi = 0; mi < 4; ++mi)
                #pragma unroll
                for (int nj = 0; nj < 4; ++nj)
                    acc[mi][nj] = __builtin_amdgcn_mfma_f32_16x16x32_bf16(
                        af[mi], bf[nj], acc[mi][nj], 0, 0, 0);
            __builtin_amdgcn_s_setprio(0);
        }

        // ---- p1 ----
        if (kt + 1 < NT) STAGE(bb ^ 1, 1, 1, kt + 1);
        {
            short8 af[4];
            #pragma unroll
            for (int mi = 0; mi < 4; ++mi)
                af[mi] = *(const short8*)&lds[bb][0][0][wr * 128 + 64 + mi * 16 + l16][pch];
            __builtin_amdgcn_s_setprio(1);
            #pragma unroll
            for (int mi = 0; mi < 4; ++mi)
                #pragma unroll
                for (int nj = 0; nj < 4; ++nj)
                    acc[4 + mi][nj] = __builtin_amdgcn_mfma_f32_16x16x32_bf16(
                        af[mi], bf[nj], acc[4 + mi][nj], 0, 0, 0);
            __builtin_amdgcn_s_setprio(0);
        }

        // ---- p2 ----
        if (kt < NT - 1) asm volatile("s_waitcnt vmcnt(8)" ::: "memory");
        else             asm volatile("s_waitcnt vmcnt(0)" ::: "memory");
        __builtin_amdgcn_s_barrier();
        __builtin_amdgcn_sched_barrier(0);
        if (kt + 2 < NT) STAGE(bb, 0, 0, kt + 2);
        #pragma unroll
        for (int nj = 0; nj < 4; ++nj)
            bf[nj] = *(const short8*)&lds[bb][1][1][wc * 64 + nj * 16 + l16][pch];
        {
            short8 af[4];
            #pragma unroll
            for (int mi = 0; mi < 4; ++mi)
                af[mi] = *(const short8*)&lds[bb][0][1][wr * 128 + mi * 16 + l16][pch];
            __builtin_amdgcn_s_setprio(1);
            #pragma unroll
            for (int mi = 0; mi < 4; ++mi)
                #pragma unroll
                for (int nj = 0; nj < 4; ++nj)
                    acc[mi][nj] = __builtin_amdgcn_mfma_f32_16x16x32_bf16(
                        af[mi], bf[nj], acc[mi][nj], 0, 0, 0);
            __builtin_amdgcn_s_setprio(0);
        }

        // ---- p3 ----
        if (kt + 2 < NT) STAGE(bb, 1, 0, kt + 2);
        {
            short8 af[4];
            #pragma unroll
            for (int mi = 0; mi < 4; ++mi)
                af[mi] = *(const short8*)&lds[bb][0][1][wr * 128 + 64 + mi * 16 + l16][pch];
            __builtin_amdgcn_s_setprio(1);
            #pragma unroll
            for (int mi = 0; mi < 4; ++mi)
                #pragma unroll
                for (int nj = 0; nj < 4; ++nj)
                    acc[4 + mi][nj] = __builtin_amdgcn_mfma_f32_16x16x32_bf16(
                        af[mi], bf[nj], acc[4 + mi][nj], 0, 0, 0);
            __builtin_amdgcn_s_setprio(0);
        }
    }

    // ---- epilogue ----
    #pragma unroll
    for (int nj = 0; nj < 4; ++nj) {
        const int n = n0 + wc * 64 + nj * 16 + l16;
        const float bv = BIAS ? bias[n] : 0.0f;
        #pragma unroll
        for (int mi = 0; mi < 8; ++mi) {
            const int mb = m0 + wr * 128 + mi * 16 + quad * 4;
            #pragma unroll
            for (int rr = 0; rr < 4; ++rr) {
                float v = acc[mi][nj][rr] + bv;
                if (SILU) v = v / (1.0f + __expf(-v));
                Cm[(size_t)(mb + rr) * N + n] = f2b(v);
            }
        }
    }
}

// ---------------- GEMM (B^T form, 128-tile): C[M,N] = A[M,K] @ Bt[N,K]^T
// Used for narrow-N GEMMs (Wo, FFN2) where 256-tiles under-fill the grid.
template<int BN, bool BIAS, bool SILU, bool RESID, bool OUTF32>
__global__ __launch_bounds__(256) void gemm_bt_kernel(
    const ushort* __restrict__ A, const ushort* __restrict__ Bt,
    const float* __restrict__ bias, const float* __restrict__ resid,
    void* __restrict__ Cm, int M, int N, int K)
{
    constexpr int NF = BN / 32;
    constexpr int BI = BN / 64;
    __shared__ __align__(16) ushort lsA[128 * 64];
    __shared__ __align__(16) ushort lsB[BN * 64];

    const int t = threadIdx.x;
    const int L = blockIdx.x + gridDim.x * blockIdx.y;
    const int cpx = (gridDim.x * gridDim.y) >> 3;
    const int wg = (L & 7) * cpx + (L >> 3);
    const int m0 = (wg / gridDim.x) * 128;
    const int n0 = (wg % gridDim.x) * BN;
    const int w = t >> 6;
    const int lane = t & 63;
    const int wm = (w >> 1) * 64;
    const int wn = (w & 1) * (BN / 2);
    const int quad = lane >> 4;
    const int l16 = lane & 15;

    const int lrow = lane >> 3;
    const int scol = ((lane & 7) ^ lrow) * 8;
    const ushort* gA = A + (size_t)(m0 + w * 32 + lrow) * K + scol;
    const ushort* gB = Bt + (size_t)(n0 + ((BI == 2) ? w * 32 : w * 16) + lrow) * K + scol;
    const int sw = l16 & 7;

    floatx4 acc[4][NF];
    #pragma unroll
    for (int i = 0; i < 4; ++i)
        #pragma unroll
        for (int j = 0; j < NF; ++j)
            acc[i][j] = (floatx4){0.f, 0.f, 0.f, 0.f};

    for (int k0 = 0; k0 < K; k0 += 64) {
        __syncthreads();
        #pragma unroll
        for (int i = 0; i < 4; ++i)
            async_cp16(gA + k0 + (size_t)(8 * i) * K, &lsA[(w * 32 + 8 * i) * 64]);
        if constexpr (BI == 2) {
            #pragma unroll
            for (int i = 0; i < 4; ++i)
                async_cp16(gB + k0 + (size_t)(8 * i) * K, &lsB[(w * 32 + 8 * i) * 64]);
        } else {
            #pragma unroll
            for (int i = 0; i < 2; ++i)
                async_cp16(gB + k0 + (size_t)(8 * i) * K, &lsB[(w * 16 + 8 * i) * 64]);
        }
        __syncthreads();

        #pragma unroll
        for (int h = 0; h < 2; ++h) {
            const int co = (((h << 2) | quad) ^ sw) * 8;
            short8 af[4], bf[NF];
            #pragma unroll
            for (int i = 0; i < 4; ++i)
                af[i] = *(const short8*)&lsA[(wm + i * 16 + l16) * 64 + co];
            #pragma unroll
            for (int j = 0; j < NF; ++j)
                bf[j] = *(const short8*)&lsB[(wn + j * 16 + l16) * 64 + co];
            #pragma unroll
            for (int i = 0; i < 4; ++i)
                #pragma unroll
                for (int j = 0; j < NF; ++j)
                    acc[i][j] = __builtin_amdgcn_mfma_f32_16x16x32_bf16(
                        af[i], bf[j], acc[i][j], 0, 0, 0);
        }
    }

    #pragma unroll
    for (int tn = 0; tn < NF; ++tn) {
        const int n = n0 + wn + tn * 16 + l16;
        const float bv = BIAS ? bias[n] : 0.0f;
        #pragma unroll
        for (int tm = 0; tm < 4; ++tm) {
            const int mbase = m0 + wm + tm * 16 + quad * 4;
            #pragma unroll
            for (int rr = 0; rr < 4; ++rr) {
                float v = acc[tm][tn][rr] + bv;
                if (SILU) v = v / (1.0f + __expf(-v));
                const size_t off = (size_t)(mbase + rr) * N + n;
                if (RESID) v += resid[off];
                if constexpr (OUTF32) ((float*)Cm)[off] = v;
                else                  ((ushort*)Cm)[off] = f2b(v);
            }
        }
    }
}

// ---------------- MFMA flash attention, paired q-tiles, 64 queries each ----
// (unchanged from round 3 — isolating the GEMM change)
__global__ __launch_bounds__(256, 4) void attn_kernel(
    const ushort* __restrict__ Qm, const ushort* __restrict__ Km,
    const ushort* __restrict__ Vm, const int* __restrict__ amask,
    ushort* __restrict__ Om, int rs)
{
    __shared__ __align__(16) ushort lsQP[64][72];   // Q staging, then PT strips
    __shared__ __align__(16) ushort lsK[64][72];
    __shared__ __align__(16) ushort lsV2[2][4096];  // subtiled V, double-buffered
    __shared__ int lsMk[64];

    const int L = blockIdx.x + (int)(gridDim.x * blockIdx.y);
    const int bh = L & 63;
    const int pr = L >> 6;                 // 0..15
    const int b = bh >> 4, h = bh & 15;
    const int t = threadIdx.x;
    const int w = t >> 6, lane = t & 63;
    const int quad = lane >> 4, l16 = lane & 15;

    const size_t base = ((size_t)b * 2048) * rs + (size_t)h * 64;
    const size_t obase = ((size_t)b * 2048) * 1024 + (size_t)h * 64;

    const int krow = t >> 3, kc8 = (t & 7) << 3;   // K staging coords
    const float scale2 = 0.125f * 1.44269504f;     // softmax in exp2 domain

    const int vkofs = ((lane >> 5) << 2) + ((lane >> 1) & 3);
    const int vdofs = ((lane >> 3) & 3) * 16 + (lane & 1) * 8;

    ushort* strip = &lsQP[w * 16][0];
    const uint strip_a = lds_u32(strip);
    char* wp_base = (char*)strip + l16 * 32 + quad * 8;   // PT write addr
    const uint rp = strip_a + quad * 256 + l16 * 8;       // PT tr-read addr

    short8 ones8;
    #pragma unroll
    for (int i = 0; i < 8; ++i) ones8[i] = (short)0x3F80;  // bf16 1.0

    #pragma unroll 1
    for (int half = 0; half < 2; ++half) {
        const int qt = half ? pr : (31 - pr);
        const int q0 = qt * 64;

        __syncthreads();   // prior half's LDS reads complete

        async_cp16(Vm + base + (size_t)(16 * w + vkofs) * rs + vdofs,
                   &lsV2[0][(4 * w) * 256]);
        async_cp16(Vm + base + (size_t)(16 * w + 8 + vkofs) * rs + vdofs,
                   &lsV2[0][(4 * w + 2) * 256]);

        #pragma unroll
        for (int it = 0; it < 2; ++it) {
            int idx = it * 256 + t;
            int row = idx >> 3, c8 = (idx & 7) << 3;
            *(int4*)&lsQP[row][c8] =
                *(const int4*)(Qm + base + (size_t)(q0 + row) * rs + c8);
        }
        __syncthreads();

        short8 aq0 = *(const short8*)&lsQP[w * 16 + l16][quad * 8];
        short8 aq1 = *(const short8*)&lsQP[w * 16 + l16][32 + quad * 8];

        floatx4 Oacc[4];
        #pragma unroll
        for (int d = 0; d < 4; ++d) Oacc[d] = (floatx4){0.f, 0.f, 0.f, 0.f};
        floatx4 Lacc = (floatx4){0.f, 0.f, 0.f, 0.f};
        float m_i[4] = {-INFINITY, -INFINITY, -INFINITY, -INFINITY};

        int4 kr0 = *(const int4*)(Km + base + (size_t)krow * rs + kc8);
        int4 kr1 = *(const int4*)(Km + base + (size_t)(32 + krow) * rs + kc8);
        int mr = amask[b * 2048 + (t & 63)];

        for (int kt = 0; kt <= qt; ++kt) {
            __syncthreads();
            *(int4*)&lsK[krow][kc8] = kr0;
            *(int4*)&lsK[32 + krow][kc8] = kr1;
            if (t < 64) lsMk[t] = mr;
            __syncthreads();

            if (kt < qt) {
                const int kn = (kt + 1) * 64;
                kr0 = *(const int4*)(Km + base + (size_t)(kn + krow) * rs + kc8);
                kr1 = *(const int4*)(Km + base + (size_t)(kn + 32 + krow) * rs + kc8);
                mr = amask[b * 2048 + kn + (t & 63)];
                ushort* vd = &lsV2[(kt + 1) & 1][0];
                async_cp16(Vm + base + (size_t)(kn + 16 * w + vkofs) * rs + vdofs,
                           vd + (4 * w) * 256);
                async_cp16(Vm + base + (size_t)(kn + 16 * w + 8 + vkofs) * rs + vdofs,
                           vd + (4 * w + 2) * 256);
            }

            // ---- QK^T ----
            floatx4 sa[4];
            #pragma unroll
            for (int j = 0; j < 4; ++j) {
                short8 bk0 = *(const short8*)&lsK[j * 16 + l16][quad * 8];
                short8 bk1 = *(const short8*)&lsK[j * 16 + l16][32 + quad * 8];
                floatx4 z = (floatx4){0.f, 0.f, 0.f, 0.f};
                z = __builtin_amdgcn_mfma_f32_16x16x32_bf16(aq0, bk0, z, 0, 0, 0);
                sa[j] = __builtin_amdgcn_mfma_f32_16x16x32_bf16(aq1, bk1, z, 0, 0, 0);
            }

            float kb[4];
            #pragma unroll
            for (int j = 0; j < 4; ++j)
                kb[j] = (lsMk[j * 16 + l16] == 1) ? 0.f : -INFINITY;
            const bool diag = (kt == qt);

            // ---- online softmax: lazy row-max ----
            float sv[4][4];
            float mxl[4];
            #pragma unroll
            for (int rr = 0; rr < 4; ++rr) {
                const int qrow = w * 16 + quad * 4 + rr;
                float mxv = -INFINITY;
                #pragma unroll
                for (int j = 0; j < 4; ++j) {
                    float v = sa[j][rr] * scale2 + kb[j];
                    if (diag) v = (j * 16 + l16 <= qrow) ? v : -INFINITY;
                    sv[rr][j] = v;
                    mxv = fmaxf(mxv, v);
                }
                mxl[rr] = mxv;
            }
            int grow = (mxl[0] > m_i[0] + 8.0f) | (mxl[1] > m_i[1] + 8.0f) |
                       (mxl[2] > m_i[2] + 8.0f) | (mxl[3] > m_i[3] + 8.0f);
            if (__any(grow)) {
                #pragma unroll
                for (int rr = 0; rr < 4; ++rr) {
                    const float mx = dpp_max16(mxl[rr]);
                    const float m_new = fmaxf(m_i[rr], mx);
                    const float al = exp2f(m_i[rr] - m_new);
                    m_i[rr] = m_new;
                    #pragma unroll
                    for (int d = 0; d < 4; ++d) Oacc[d][rr] *= al;
                    Lacc[rr] *= al;
                }
            }

            // ---- P -> PT strip [64 k][16 q] ----
            #pragma unroll
            for (int j = 0; j < 4; ++j) {
                float p0 = exp2f(sv[0][j] - m_i[0]);
                float p1 = exp2f(sv[1][j] - m_i[1]);
                float p2 = exp2f(sv[2][j] - m_i[2]);
                float p3 = exp2f(sv[3][j] - m_i[3]);
                uint w0, w1;
                asm("v_cvt_pk_bf16_f32 %0, %1, %2" : "=v"(w0) : "v"(p0), "v"(p1));
                asm("v_cvt_pk_bf16_f32 %0, %1, %2" : "=v"(w1) : "v"(p2), "v"(p3));
                *(uint2*)(wp_base + j * 512) = make_uint2(w0, w1);
            }

            // ---- PT -> A-frags via hardware transpose reads ----
            asm volatile("s_waitcnt lgkmcnt(0)" ::: "memory");
            uintx2 t0, t1, t2, t3;
            asm volatile("ds_read_b64_tr_b16 %0, %1 offset:0"    : "=v"(t0) : "v"(rp));
            asm volatile("ds_read_b64_tr_b16 %0, %1 offset:128"  : "=v"(t1) : "v"(rp));
            asm volatile("ds_read_b64_tr_b16 %0, %1 offset:1024" : "=v"(t2) : "v"(rp));
            asm volatile("ds_read_b64_tr_b16 %0, %1 offset:1152" : "=v"(t3) : "v"(rp));
            asm volatile("s_waitcnt lgkmcnt(0)" ::: "memory");
            __builtin_amdgcn_sched_barrier(0);
            union { short8 s; uint u[4]; } ua0, ua1;
            ua0.u[0] = t0.x; ua0.u[1] = t0.y; ua0.u[2] = t1.x; ua0.u[3] = t1.y;
            ua1.u[0] = t2.x; ua1.u[1] = t2.y; ua1.u[2] = t3.x; ua1.u[3] = t3.y;
            const short8 ap0 = ua0.s;
            const short8 ap1 = ua1.s;

            // ---- PV + L ----
            const uint vb = lds_u32(&lsV2[kt & 1][0]) + quad * 1024 + l16 * 8;
            #pragma unroll
            for (int db = 0; db < 4; ++db) {
                const uint vbd = vb + db * 128;
                uintx2 v0, v1, v2, v3;
                asm volatile("ds_read_b64_tr_b16 %0, %1 offset:0"    : "=v"(v0) : "v"(vbd));
                asm volatile("ds_read_b64_tr_b16 %0, %1 offset:512"  : "=v"(v1) : "v"(vbd));
                asm volatile("ds_read_b64_tr_b16 %0, %1 offset:4096" : "=v"(v2) : "v"(vbd));
                asm volatile("ds_read_b64_tr_b16 %0, %1 offset:4608" : "=v"(v3) : "v"(vbd));
                asm volatile("s_waitcnt lgkmcnt(0)" ::: "memory");
                __builtin_amdgcn_sched_barrier(0);
                union { short8 s; uint u[4]; } ub0, ub1;
                ub0.u[0] = v0.x; ub0.u[1] = v0.y; ub0.u[2] = v1.x; ub0.u[3] = v1.y;
                ub1.u[0] = v2.x; ub1.u[1] = v2.y; ub1.u[2] = v3.x; ub1.u[3] = v3.y;
                Oacc[db] = __builtin_amdgcn_mfma_f32_16x16x32_bf16(ap0, ub0.s, Oacc[db], 0, 0, 0);
                Oacc[db] = __builtin_amdgcn_mfma_f32_16x16x32_bf16(ap1, ub1.s, Oacc[db], 0, 0, 0);
            }
            Lacc = __builtin_amdgcn_mfma_f32_16x16x32_bf16(ap0, ones8, Lacc, 0, 0, 0);
            Lacc = __builtin_amdgcn_mfma_f32_16x16x32_bf16(ap1, ones8, Lacc, 0, 0, 0);
        }

        #pragma unroll
        for (int rr = 0; rr < 4; ++rr) {
            const float inv = 1.0f / Lacc[rr];
            const int row = q0 + w * 16 + quad * 4 + rr;
            ushort* op = Om + obase + (size_t)row * 1024;
            #pragma unroll
            for (int d = 0; d < 4; ++d)
                op[d * 16 + l16] = f2b(Oacc[d][rr] * inv);
        }
    }
}

// ---------------- driver ----------------
// ws peak 72 MiB:
//   phase 1: xa [0,16) | qkvb [16,64) | Wqkv_t [64,70) | Wo_t [70,72)
//   phase 2: W1_t [0,8) W2_t [8,16) | yb [16,32) | hb chunk [32,64)
extern "C" void kernel_launch(void* const* d_in, const int* in_sizes, int n_in,
                              void* d_out, int out_size, void* d_ws, size_t ws_size,
                              hipStream_t stream) {
    const float* hidden = (const float*)d_in[0];
    const int*   amask  = (const int*)d_in[1];
    const float* Wq  = (const float*)d_in[2];
    const float* Wk  = (const float*)d_in[3];
    const float* Wv  = (const float*)d_in[4];
    const float* Wo  = (const float*)d_in[5];
    const float* l1g = (const float*)d_in[6];
    const float* l1b = (const float*)d_in[7];
    const float* W1  = (const float*)d_in[8];
    const float* b1  = (const float*)d_in[9];
    const float* W2  = (const float*)d_in[10];
    const float* b2  = (const float*)d_in[11];
    const float* l2g = (const float*)d_in[12];
    const float* l2b = (const float*)d_in[13];

    const int M = 8192;
    const size_t MB = 1048576;
    char* ws = (char*)d_ws;
    ushort* xa    = (ushort*)(ws);
    ushort* qkvb  = (ushort*)(ws + 16 * MB);
    ushort* Wqkvt = (ushort*)(ws + 64 * MB);
    ushort* Wot   = (ushort*)(ws + 70 * MB);
    ushort* W1t   = (ushort*)(ws);
    ushort* W2t   = (ushort*)(ws + 8 * MB);
    ushort* yb    = (ushort*)(ws + 16 * MB);
    ushort* hbc   = (ushort*)(ws + 32 * MB);
    float*  x2    = (float*)d_out;

    cvt_t_kernel<<<dim3(32, 32), 256, 0, stream>>>(Wq, Wqkvt, 1024, 1024);
    cvt_t_kernel<<<dim3(32, 32), 256, 0, stream>>>(Wk, Wqkvt + (size_t)1024 * 1024, 1024, 1024);
    cvt_t_kernel<<<dim3(32, 32), 256, 0, stream>>>(Wv, Wqkvt + (size_t)2048 * 1024, 1024, 1024);
    cvt_t_kernel<<<dim3(32, 32), 256, 0, stream>>>(Wo, Wot, 1024, 1024);

    ln_kernel<<<M, 256, 0, stream>>>(hidden, l1g, l1b, xa);
    gemm256_kernel<false, false><<<dim3(12, 32), 512, 0, stream>>>(
        xa, Wqkvt, nullptr, qkvb, M, 3072, 1024);
    attn_kernel<<<dim3(16, 64), 256, 0, stream>>>(
        qkvb, qkvb + 1024, qkvb + 2048, amask, xa, 3072);
    gemm_bt_kernel<64, false, false, true, true><<<dim3(16, 64), 256, 0, stream>>>(
        xa, Wot, nullptr, hidden, x2, M, 1024, 1024);

    cvt_t_kernel<<<dim3(128, 32), 256, 0, stream>>>(W1, W1t, 1024, 4096);
    cvt_t_kernel<<<dim3(32, 128), 256, 0, stream>>>(W2, W2t, 4096, 1024);

    ln_kernel<<<M, 256, 0, stream>>>(x2, l2g, l2b, yb);
    for (int mc = 0; mc < 2; ++mc) {
        const size_t off = (size_t)mc * 4096 * 1024;
        gemm256_kernel<true, true><<<dim3(16, 16), 512, 0, stream>>>(
            yb + off, W1t, b1, hbc, 4096, 4096, 1024);
        gemm_bt_kernel<64, true, false, true, true><<<dim3(16, 32), 256, 0, stream>>>(
            hbc, W2t, b2, x2 + off, (void*)(x2 + off), 4096, 1024, 4096);
    }
}

// Round 5
// 557.968 us; speedup vs baseline: 1.2769x; 1.0090x over previous
//
#include <hip/hip_runtime.h>
#include <math.h>

typedef __attribute__((ext_vector_type(8))) short short8;
typedef __attribute__((ext_vector_type(4))) float floatx4;
typedef __attribute__((ext_vector_type(2))) unsigned int uintx2;

__device__ __forceinline__ float b2f(ushort u) {
    union { uint i; float f; } c; c.i = ((uint)u) << 16; return c.f;
}
__device__ __forceinline__ ushort f2b(float f) {
    union { float f; uint i; } c; c.f = f;
    return (ushort)((c.i + 0x7fffu + ((c.i >> 16) & 1u)) >> 16);
}

__device__ __forceinline__ void async_cp16(const ushort* g, ushort* l) {
    __builtin_amdgcn_global_load_lds(
        (const __attribute__((address_space(1))) void*)g,
        (__attribute__((address_space(3))) void*)l, 16, 0, 0);
}

__device__ __forceinline__ uint lds_u32(const void* p) {
    return (uint)(uintptr_t)(const __attribute__((address_space(3))) void*)p;
}

// max-reduce over the 16-lane DPP row using full-rate VALU DPP ops
__device__ __forceinline__ float dpp_max16(float x) {
    int y;
    y = __builtin_amdgcn_update_dpp(__float_as_int(x), __float_as_int(x), 0xB1, 0xF, 0xF, false);
    x = fmaxf(x, __int_as_float(y));
    y = __builtin_amdgcn_update_dpp(__float_as_int(x), __float_as_int(x), 0x4E, 0xF, 0xF, false);
    x = fmaxf(x, __int_as_float(y));
    y = __builtin_amdgcn_update_dpp(__float_as_int(x), __float_as_int(x), 0x141, 0xF, 0xF, false);
    x = fmaxf(x, __int_as_float(y));
    y = __builtin_amdgcn_update_dpp(__float_as_int(x), __float_as_int(x), 0x140, 0xF, 0xF, false);
    x = fmaxf(x, __int_as_float(y));
    return x;
}

// ---------------- fp32 [K,N] -> bf16 transposed [N,K] ----------------
__global__ __launch_bounds__(256) void cvt_t_kernel(
    const float* __restrict__ S, ushort* __restrict__ D, int K, int N)
{
    __shared__ float ls[32][33];
    const int k0 = blockIdx.y * 32, n0 = blockIdx.x * 32;
    const int t = threadIdx.x;
    const int kr = t >> 3, nc = (t & 7) * 4;
    float4 f = *(const float4*)(S + (size_t)(k0 + kr) * N + n0 + nc);
    ls[kr][nc] = f.x; ls[kr][nc + 1] = f.y; ls[kr][nc + 2] = f.z; ls[kr][nc + 3] = f.w;
    __syncthreads();
    const int nr = t >> 3, kc = (t & 7) * 4;
    ushort4 o;
    o.x = f2b(ls[kc][nr]); o.y = f2b(ls[kc + 1][nr]);
    o.z = f2b(ls[kc + 2][nr]); o.w = f2b(ls[kc + 3][nr]);
    *(ushort4*)(D + (size_t)(n0 + nr) * K + k0 + kc) = o;
}

// ---------------- LayerNorm: fp32 in, bf16 out ----------------
__global__ __launch_bounds__(256) void ln_kernel(
    const float* __restrict__ X, const float* __restrict__ G,
    const float* __restrict__ Bb, ushort* __restrict__ Y)
{
    const int row = blockIdx.x;
    const int t = threadIdx.x;
    const float* xr = X + (size_t)row * 1024;
    float4 p = ((const float4*)xr)[t];
    float s = p.x + p.y + p.z + p.w;
    float s2 = p.x * p.x + p.y * p.y + p.z * p.z + p.w * p.w;
    #pragma unroll
    for (int off = 32; off > 0; off >>= 1) {
        s += __shfl_down(s, off);
        s2 += __shfl_down(s2, off);
    }
    __shared__ float rs1[4], rs2[4];
    if ((t & 63) == 0) { rs1[t >> 6] = s; rs2[t >> 6] = s2; }
    __syncthreads();
    float S1 = rs1[0] + rs1[1] + rs1[2] + rs1[3];
    float S2 = rs2[0] + rs2[1] + rs2[2] + rs2[3];
    float mu = S1 * (1.0f / 1024.0f);
    float var = S2 * (1.0f / 1024.0f) - mu * mu;
    float rstd = rsqrtf(var + 1e-12f);
    float4 gp = ((const float4*)G)[t];
    float4 bp = ((const float4*)Bb)[t];
    ushort4 o;
    o.x = f2b((p.x - mu) * rstd * gp.x + bp.x);
    o.y = f2b((p.y - mu) * rstd * gp.y + bp.y);
    o.z = f2b((p.z - mu) * rstd * gp.z + bp.z);
    o.w = f2b((p.w - mu) * rstd * gp.w + bp.w);
    ((ushort4*)(Y + (size_t)row * 1024))[t] = o;
}

// ---------------- 256x256 8-phase GEMM (T2+T3+T4+T5): C = A @ Bt^T ----------
// 512 threads (8 waves, 2M x 4N), BK=64, LDS [2buf][A/B][ks][256][32] = 128KB.
// SWIZZLE (fixed r5): rows are 64B = 4 chunks of 16B; bank-slot index is
// (4*(row&1) + chunk) mod 8, so the involution must be chunk ^= (row>>1)&3
// (NOT row&3, which collapses frag reads onto 4 slots -> 4-way conflict).
// With (row>>1)&3 the 16 frag rows walk all 8 slots twice -> free 2-way.
// Applied via pre-swizzled GLOBAL source (rule 21) + same XOR on ds_read.
// Schedule per K-tile kt (4 phases of 16 MFMA):
//   p0: vmcnt(8)+s_barrier; stage Ha1(kt+1); read B[ks0],A[ks0,mh0]; MFMA
//   p1:                     stage Hb1(kt+1); read A[ks0,mh1];        MFMA
//   p2: vmcnt(8)+s_barrier; stage Ha0(kt+2); read B[ks1],A[ks1,mh0]; MFMA
//   p3:                     stage Hb0(kt+2); read A[ks1,mh1];        MFMA
// Steady state: 12 loads in flight before each wait, trimmed to 8 (4 halves).
// Tail: waits peel 8 -> 4 -> 0.
template<bool BIAS, bool SILU>
__global__ __launch_bounds__(512, 2) void gemm256_kernel(
    const ushort* __restrict__ A, const ushort* __restrict__ Bt,
    const float* __restrict__ bias, ushort* __restrict__ Cm,
    int M, int N, int K)
{
    __shared__ __align__(16) ushort lds[2][2][2][256][32];

    const int t = threadIdx.x;
    const int L = blockIdx.x + (int)(gridDim.x * blockIdx.y);
    const int cpx = (int)(gridDim.x * gridDim.y) >> 3;
    const int wg = (L & 7) * cpx + (L >> 3);
    const int m0 = (wg / gridDim.x) * 256;
    const int n0 = (wg % gridDim.x) * 256;
    const int w = t >> 6, lane = t & 63;
    const int wr = w >> 2, wc = w & 3;
    const int quad = lane >> 4, l16 = lane & 15;

    // staging lane map: row = w*16 + (lane>>2) (+128 for round 1),
    // phys chunk = lane&3; source logical chunk = phys ^ ((row>>1)&3)
    // (+128 preserves (row>>1)&3 since 128 == 0 mod 8)
    const int srow = lane >> 2;
    const int schunk = ((lane & 3) ^ ((srow >> 1) & 3)) * 8;
    const ushort* gA = A + (size_t)(m0 + w * 16 + srow) * K + schunk;
    const ushort* gB = Bt + (size_t)(n0 + w * 16 + srow) * K + schunk;
    const int NT = K >> 6;

    // frag-read phys chunk: logical chunk = quad; row = base16 + l16 so
    // (row>>1)&3 == (l16>>1)&3
    const int pch = (quad ^ ((l16 >> 1) & 3)) * 8;

    floatx4 acc[8][4];
    #pragma unroll
    for (int i = 0; i < 8; ++i)
        #pragma unroll
        for (int j = 0; j < 4; ++j)
            acc[i][j] = (floatx4){0.f, 0.f, 0.f, 0.f};

    auto STAGE = [&](int bb, int mat, int ks, int kt) {
        const ushort* g = (mat ? gB : gA) + (size_t)kt * 64 + ks * 32;
        ushort* l0 = &lds[bb][mat][ks][w * 16][0];
        async_cp16(g, l0);
        async_cp16(g + (size_t)128 * K, l0 + 128 * 32);
    };

    // prologue: Ha0(0) Hb0(0) Ha1(0) Hb1(0) Ha0(1) Hb0(1) -> 12 loads in flight
    STAGE(0, 0, 0, 0); STAGE(0, 1, 0, 0);
    STAGE(0, 0, 1, 0); STAGE(0, 1, 1, 0);
    STAGE(1, 0, 0, 1); STAGE(1, 1, 0, 1);

    #pragma unroll 1
    for (int kt = 0; kt < NT; ++kt) {
        const int bb = kt & 1;
        short8 bf[4];

        // ---- p0 ----
        if (kt < NT - 1) asm volatile("s_waitcnt vmcnt(8)" ::: "memory");
        else             asm volatile("s_waitcnt vmcnt(4)" ::: "memory");
        __builtin_amdgcn_s_barrier();
        __builtin_amdgcn_sched_barrier(0);
        if (kt + 1 < NT) STAGE(bb ^ 1, 0, 1, kt + 1);
        #pragma unroll
        for (int nj = 0; nj < 4; ++nj)
            bf[nj] = *(const short8*)&lds[bb][1][0][wc * 64 + nj * 16 + l16][pch];
        {
            short8 af[4];
            #pragma unroll
            for (int mi = 0; mi < 4; ++mi)
                af[mi] = *(const short8*)&lds[bb][0][0][wr * 128 + mi * 16 + l16][pch];
            __builtin_amdgcn_s_setprio(1);
            #pragma unroll
            for (int mi = 0; mi < 4; ++mi)
                #pragma unroll
                for (int nj = 0; nj < 4; ++nj)
                    acc[mi][nj] = __builtin_amdgcn_mfma_f32_16x16x32_bf16(
                        af[mi], bf[nj], acc[mi][nj], 0, 0, 0);
            __builtin_amdgcn_s_setprio(0);
        }

        // ---- p1 ----
        if (kt + 1 < NT) STAGE(bb ^ 1, 1, 1, kt + 1);
        {
            short8 af[4];
            #pragma unroll
            for (int mi = 0; mi < 4; ++mi)
                af[mi] = *(const short8*)&lds[bb][0][0][wr * 128 + 64 + mi * 16 + l16][pch];
            __builtin_amdgcn_s_setprio(1);
            #pragma unroll
            for (int mi = 0; mi < 4; ++mi)
                #pragma unroll
                for (int nj = 0; nj < 4; ++nj)
                    acc[4 + mi][nj] = __builtin_amdgcn_mfma_f32_16x16x32_bf16(
                        af[mi], bf[nj], acc[4 + mi][nj], 0, 0, 0);
            __builtin_amdgcn_s_setprio(0);
        }

        // ---- p2 ----
        if (kt < NT - 1) asm volatile("s_waitcnt vmcnt(8)" ::: "memory");
        else             asm volatile("s_waitcnt vmcnt(0)" ::: "memory");
        __builtin_amdgcn_s_barrier();
        __builtin_amdgcn_sched_barrier(0);
        if (kt + 2 < NT) STAGE(bb, 0, 0, kt + 2);
        #pragma unroll
        for (int nj = 0; nj < 4; ++nj)
            bf[nj] = *(const short8*)&lds[bb][1][1][wc * 64 + nj * 16 + l16][pch];
        {
            short8 af[4];
            #pragma unroll
            for (int mi = 0; mi < 4; ++mi)
                af[mi] = *(const short8*)&lds[bb][0][1][wr * 128 + mi * 16 + l16][pch];
            __builtin_amdgcn_s_setprio(1);
            #pragma unroll
            for (int mi = 0; mi < 4; ++mi)
                #pragma unroll
                for (int nj = 0; nj < 4; ++nj)
                    acc[mi][nj] = __builtin_amdgcn_mfma_f32_16x16x32_bf16(
                        af[mi], bf[nj], acc[mi][nj], 0, 0, 0);
            __builtin_amdgcn_s_setprio(0);
        }

        // ---- p3 ----
        if (kt + 2 < NT) STAGE(bb, 1, 0, kt + 2);
        {
            short8 af[4];
            #pragma unroll
            for (int mi = 0; mi < 4; ++mi)
                af[mi] = *(const short8*)&lds[bb][0][1][wr * 128 + 64 + mi * 16 + l16][pch];
            __builtin_amdgcn_s_setprio(1);
            #pragma unroll
            for (int mi = 0; mi < 4; ++mi)
                #pragma unroll
                for (int nj = 0; nj < 4; ++nj)
                    acc[4 + mi][nj] = __builtin_amdgcn_mfma_f32_16x16x32_bf16(
                        af[mi], bf[nj], acc[4 + mi][nj], 0, 0, 0);
            __builtin_amdgcn_s_setprio(0);
        }
    }

    // ---- epilogue ----
    #pragma unroll
    for (int nj = 0; nj < 4; ++nj) {
        const int n = n0 + wc * 64 + nj * 16 + l16;
        const float bv = BIAS ? bias[n] : 0.0f;
        #pragma unroll
        for (int mi = 0; mi < 8; ++mi) {
            const int mb = m0 + wr * 128 + mi * 16 + quad * 4;
            #pragma unroll
            for (int rr = 0; rr < 4; ++rr) {
                float v = acc[mi][nj][rr] + bv;
                if (SILU) v = v / (1.0f + __expf(-v));
                Cm[(size_t)(mb + rr) * N + n] = f2b(v);
            }
        }
    }
}

// ---------------- GEMM (B^T form, 128-tile): C[M,N] = A[M,K] @ Bt[N,K]^T
// Used for narrow-N GEMMs (Wo, FFN2) where 256-tiles under-fill the grid.
template<int BN, bool BIAS, bool SILU, bool RESID, bool OUTF32>
__global__ __launch_bounds__(256) void gemm_bt_kernel(
    const ushort* __restrict__ A, const ushort* __restrict__ Bt,
    const float* __restrict__ bias, const float* __restrict__ resid,
    void* __restrict__ Cm, int M, int N, int K)
{
    constexpr int NF = BN / 32;
    constexpr int BI = BN / 64;
    __shared__ __align__(16) ushort lsA[128 * 64];
    __shared__ __align__(16) ushort lsB[BN * 64];

    const int t = threadIdx.x;
    const int L = blockIdx.x + gridDim.x * blockIdx.y;
    const int cpx = (gridDim.x * gridDim.y) >> 3;
    const int wg = (L & 7) * cpx + (L >> 3);
    const int m0 = (wg / gridDim.x) * 128;
    const int n0 = (wg % gridDim.x) * BN;
    const int w = t >> 6;
    const int lane = t & 63;
    const int wm = (w >> 1) * 64;
    const int wn = (w & 1) * (BN / 2);
    const int quad = lane >> 4;
    const int l16 = lane & 15;

    const int lrow = lane >> 3;
    const int scol = ((lane & 7) ^ lrow) * 8;
    const ushort* gA = A + (size_t)(m0 + w * 32 + lrow) * K + scol;
    const ushort* gB = Bt + (size_t)(n0 + ((BI == 2) ? w * 32 : w * 16) + lrow) * K + scol;
    const int sw = l16 & 7;

    floatx4 acc[4][NF];
    #pragma unroll
    for (int i = 0; i < 4; ++i)
        #pragma unroll
        for (int j = 0; j < NF; ++j)
            acc[i][j] = (floatx4){0.f, 0.f, 0.f, 0.f};

    for (int k0 = 0; k0 < K; k0 += 64) {
        __syncthreads();
        #pragma unroll
        for (int i = 0; i < 4; ++i)
            async_cp16(gA + k0 + (size_t)(8 * i) * K, &lsA[(w * 32 + 8 * i) * 64]);
        if constexpr (BI == 2) {
            #pragma unroll
            for (int i = 0; i < 4; ++i)
                async_cp16(gB + k0 + (size_t)(8 * i) * K, &lsB[(w * 32 + 8 * i) * 64]);
        } else {
            #pragma unroll
            for (int i = 0; i < 2; ++i)
                async_cp16(gB + k0 + (size_t)(8 * i) * K, &lsB[(w * 16 + 8 * i) * 64]);
        }
        __syncthreads();

        #pragma unroll
        for (int h = 0; h < 2; ++h) {
            const int co = (((h << 2) | quad) ^ sw) * 8;
            short8 af[4], bf[NF];
            #pragma unroll
            for (int i = 0; i < 4; ++i)
                af[i] = *(const short8*)&lsA[(wm + i * 16 + l16) * 64 + co];
            #pragma unroll
            for (int j = 0; j < NF; ++j)
                bf[j] = *(const short8*)&lsB[(wn + j * 16 + l16) * 64 + co];
            #pragma unroll
            for (int i = 0; i < 4; ++i)
                #pragma unroll
                for (int j = 0; j < NF; ++j)
                    acc[i][j] = __builtin_amdgcn_mfma_f32_16x16x32_bf16(
                        af[i], bf[j], acc[i][j], 0, 0, 0);
        }
    }

    #pragma unroll
    for (int tn = 0; tn < NF; ++tn) {
        const int n = n0 + wn + tn * 16 + l16;
        const float bv = BIAS ? bias[n] : 0.0f;
        #pragma unroll
        for (int tm = 0; tm < 4; ++tm) {
            const int mbase = m0 + wm + tm * 16 + quad * 4;
            #pragma unroll
            for (int rr = 0; rr < 4; ++rr) {
                float v = acc[tm][tn][rr] + bv;
                if (SILU) v = v / (1.0f + __expf(-v));
                const size_t off = (size_t)(mbase + rr) * N + n;
                if (RESID) v += resid[off];
                if constexpr (OUTF32) ((float*)Cm)[off] = v;
                else                  ((ushort*)Cm)[off] = f2b(v);
            }
        }
    }
}

// ---------------- MFMA flash attention, paired q-tiles, 64 queries each ----
// (unchanged — isolating the gemm256 swizzle fix)
__global__ __launch_bounds__(256, 4) void attn_kernel(
    const ushort* __restrict__ Qm, const ushort* __restrict__ Km,
    const ushort* __restrict__ Vm, const int* __restrict__ amask,
    ushort* __restrict__ Om, int rs)
{
    __shared__ __align__(16) ushort lsQP[64][72];   // Q staging, then PT strips
    __shared__ __align__(16) ushort lsK[64][72];
    __shared__ __align__(16) ushort lsV2[2][4096];  // subtiled V, double-buffered
    __shared__ int lsMk[64];

    const int L = blockIdx.x + (int)(gridDim.x * blockIdx.y);
    const int bh = L & 63;
    const int pr = L >> 6;                 // 0..15
    const int b = bh >> 4, h = bh & 15;
    const int t = threadIdx.x;
    const int w = t >> 6, lane = t & 63;
    const int quad = lane >> 4, l16 = lane & 15;

    const size_t base = ((size_t)b * 2048) * rs + (size_t)h * 64;
    const size_t obase = ((size_t)b * 2048) * 1024 + (size_t)h * 64;

    const int krow = t >> 3, kc8 = (t & 7) << 3;   // K staging coords
    const float scale2 = 0.125f * 1.44269504f;     // softmax in exp2 domain

    const int vkofs = ((lane >> 5) << 2) + ((lane >> 1) & 3);
    const int vdofs = ((lane >> 3) & 3) * 16 + (lane & 1) * 8;

    ushort* strip = &lsQP[w * 16][0];
    const uint strip_a = lds_u32(strip);
    char* wp_base = (char*)strip + l16 * 32 + quad * 8;   // PT write addr
    const uint rp = strip_a + quad * 256 + l16 * 8;       // PT tr-read addr

    short8 ones8;
    #pragma unroll
    for (int i = 0; i < 8; ++i) ones8[i] = (short)0x3F80;  // bf16 1.0

    #pragma unroll 1
    for (int half = 0; half < 2; ++half) {
        const int qt = half ? pr : (31 - pr);
        const int q0 = qt * 64;

        __syncthreads();   // prior half's LDS reads complete

        async_cp16(Vm + base + (size_t)(16 * w + vkofs) * rs + vdofs,
                   &lsV2[0][(4 * w) * 256]);
        async_cp16(Vm + base + (size_t)(16 * w + 8 + vkofs) * rs + vdofs,
                   &lsV2[0][(4 * w + 2) * 256]);

        #pragma unroll
        for (int it = 0; it < 2; ++it) {
            int idx = it * 256 + t;
            int row = idx >> 3, c8 = (idx & 7) << 3;
            *(int4*)&lsQP[row][c8] =
                *(const int4*)(Qm + base + (size_t)(q0 + row) * rs + c8);
        }
        __syncthreads();

        short8 aq0 = *(const short8*)&lsQP[w * 16 + l16][quad * 8];
        short8 aq1 = *(const short8*)&lsQP[w * 16 + l16][32 + quad * 8];

        floatx4 Oacc[4];
        #pragma unroll
        for (int d = 0; d < 4; ++d) Oacc[d] = (floatx4){0.f, 0.f, 0.f, 0.f};
        floatx4 Lacc = (floatx4){0.f, 0.f, 0.f, 0.f};
        float m_i[4] = {-INFINITY, -INFINITY, -INFINITY, -INFINITY};

        int4 kr0 = *(const int4*)(Km + base + (size_t)krow * rs + kc8);
        int4 kr1 = *(const int4*)(Km + base + (size_t)(32 + krow) * rs + kc8);
        int mr = amask[b * 2048 + (t & 63)];

        for (int kt = 0; kt <= qt; ++kt) {
            __syncthreads();
            *(int4*)&lsK[krow][kc8] = kr0;
            *(int4*)&lsK[32 + krow][kc8] = kr1;
            if (t < 64) lsMk[t] = mr;
            __syncthreads();

            if (kt < qt) {
                const int kn = (kt + 1) * 64;
                kr0 = *(const int4*)(Km + base + (size_t)(kn + krow) * rs + kc8);
                kr1 = *(const int4*)(Km + base + (size_t)(kn + 32 + krow) * rs + kc8);
                mr = amask[b * 2048 + kn + (t & 63)];
                ushort* vd = &lsV2[(kt + 1) & 1][0];
                async_cp16(Vm + base + (size_t)(kn + 16 * w + vkofs) * rs + vdofs,
                           vd + (4 * w) * 256);
                async_cp16(Vm + base + (size_t)(kn + 16 * w + 8 + vkofs) * rs + vdofs,
                           vd + (4 * w + 2) * 256);
            }

            // ---- QK^T ----
            floatx4 sa[4];
            #pragma unroll
            for (int j = 0; j < 4; ++j) {
                short8 bk0 = *(const short8*)&lsK[j * 16 + l16][quad * 8];
                short8 bk1 = *(const short8*)&lsK[j * 16 + l16][32 + quad * 8];
                floatx4 z = (floatx4){0.f, 0.f, 0.f, 0.f};
                z = __builtin_amdgcn_mfma_f32_16x16x32_bf16(aq0, bk0, z, 0, 0, 0);
                sa[j] = __builtin_amdgcn_mfma_f32_16x16x32_bf16(aq1, bk1, z, 0, 0, 0);
            }

            float kb[4];
            #pragma unroll
            for (int j = 0; j < 4; ++j)
                kb[j] = (lsMk[j * 16 + l16] == 1) ? 0.f : -INFINITY;
            const bool diag = (kt == qt);

            // ---- online softmax: lazy row-max ----
            float sv[4][4];
            float mxl[4];
            #pragma unroll
            for (int rr = 0; rr < 4; ++rr) {
                const int qrow = w * 16 + quad * 4 + rr;
                float mxv = -INFINITY;
                #pragma unroll
                for (int j = 0; j < 4; ++j) {
                    float v = sa[j][rr] * scale2 + kb[j];
                    if (diag) v = (j * 16 + l16 <= qrow) ? v : -INFINITY;
                    sv[rr][j] = v;
                    mxv = fmaxf(mxv, v);
                }
                mxl[rr] = mxv;
            }
            int grow = (mxl[0] > m_i[0] + 8.0f) | (mxl[1] > m_i[1] + 8.0f) |
                       (mxl[2] > m_i[2] + 8.0f) | (mxl[3] > m_i[3] + 8.0f);
            if (__any(grow)) {
                #pragma unroll
                for (int rr = 0; rr < 4; ++rr) {
                    const float mx = dpp_max16(mxl[rr]);
                    const float m_new = fmaxf(m_i[rr], mx);
                    const float al = exp2f(m_i[rr] - m_new);
                    m_i[rr] = m_new;
                    #pragma unroll
                    for (int d = 0; d < 4; ++d) Oacc[d][rr] *= al;
                    Lacc[rr] *= al;
                }
            }

            // ---- P -> PT strip [64 k][16 q] ----
            #pragma unroll
            for (int j = 0; j < 4; ++j) {
                float p0 = exp2f(sv[0][j] - m_i[0]);
                float p1 = exp2f(sv[1][j] - m_i[1]);
                float p2 = exp2f(sv[2][j] - m_i[2]);
                float p3 = exp2f(sv[3][j] - m_i[3]);
                uint w0, w1;
                asm("v_cvt_pk_bf16_f32 %0, %1, %2" : "=v"(w0) : "v"(p0), "v"(p1));
                asm("v_cvt_pk_bf16_f32 %0, %1, %2" : "=v"(w1) : "v"(p2), "v"(p3));
                *(uint2*)(wp_base + j * 512) = make_uint2(w0, w1);
            }

            // ---- PT -> A-frags via hardware transpose reads ----
            asm volatile("s_waitcnt lgkmcnt(0)" ::: "memory");
            uintx2 t0, t1, t2, t3;
            asm volatile("ds_read_b64_tr_b16 %0, %1 offset:0"    : "=v"(t0) : "v"(rp));
            asm volatile("ds_read_b64_tr_b16 %0, %1 offset:128"  : "=v"(t1) : "v"(rp));
            asm volatile("ds_read_b64_tr_b16 %0, %1 offset:1024" : "=v"(t2) : "v"(rp));
            asm volatile("ds_read_b64_tr_b16 %0, %1 offset:1152" : "=v"(t3) : "v"(rp));
            asm volatile("s_waitcnt lgkmcnt(0)" ::: "memory");
            __builtin_amdgcn_sched_barrier(0);
            union { short8 s; uint u[4]; } ua0, ua1;
            ua0.u[0] = t0.x; ua0.u[1] = t0.y; ua0.u[2] = t1.x; ua0.u[3] = t1.y;
            ua1.u[0] = t2.x; ua1.u[1] = t2.y; ua1.u[2] = t3.x; ua1.u[3] = t3.y;
            const short8 ap0 = ua0.s;
            const short8 ap1 = ua1.s;

            // ---- PV + L ----
            const uint vb = lds_u32(&lsV2[kt & 1][0]) + quad * 1024 + l16 * 8;
            #pragma unroll
            for (int db = 0; db < 4; ++db) {
                const uint vbd = vb + db * 128;
                uintx2 v0, v1, v2, v3;
                asm volatile("ds_read_b64_tr_b16 %0, %1 offset:0"    : "=v"(v0) : "v"(vbd));
                asm volatile("ds_read_b64_tr_b16 %0, %1 offset:512"  : "=v"(v1) : "v"(vbd));
                asm volatile("ds_read_b64_tr_b16 %0, %1 offset:4096" : "=v"(v2) : "v"(vbd));
                asm volatile("ds_read_b64_tr_b16 %0, %1 offset:4608" : "=v"(v3) : "v"(vbd));
                asm volatile("s_waitcnt lgkmcnt(0)" ::: "memory");
                __builtin_amdgcn_sched_barrier(0);
                union { short8 s; uint u[4]; } ub0, ub1;
                ub0.u[0] = v0.x; ub0.u[1] = v0.y; ub0.u[2] = v1.x; ub0.u[3] = v1.y;
                ub1.u[0] = v2.x; ub1.u[1] = v2.y; ub1.u[2] = v3.x; ub1.u[3] = v3.y;
                Oacc[db] = __builtin_amdgcn_mfma_f32_16x16x32_bf16(ap0, ub0.s, Oacc[db], 0, 0, 0);
                Oacc[db] = __builtin_amdgcn_mfma_f32_16x16x32_bf16(ap1, ub1.s, Oacc[db], 0, 0, 0);
            }
            Lacc = __builtin_amdgcn_mfma_f32_16x16x32_bf16(ap0, ones8, Lacc, 0, 0, 0);
            Lacc = __builtin_amdgcn_mfma_f32_16x16x32_bf16(ap1, ones8, Lacc, 0, 0, 0);
        }

        #pragma unroll
        for (int rr = 0; rr < 4; ++rr) {
            const float inv = 1.0f / Lacc[rr];
            const int row = q0 + w * 16 + quad * 4 + rr;
            ushort* op = Om + obase + (size_t)row * 1024;
            #pragma unroll
            for (int d = 0; d < 4; ++d)
                op[d * 16 + l16] = f2b(Oacc[d][rr] * inv);
        }
    }
}

// ---------------- driver ----------------
// ws peak 72 MiB:
//   phase 1: xa [0,16) | qkvb [16,64) | Wqkv_t [64,70) | Wo_t [70,72)
//   phase 2: W1_t [0,8) W2_t [8,16) | yb [16,32) | hb chunk [32,64)
extern "C" void kernel_launch(void* const* d_in, const int* in_sizes, int n_in,
                              void* d_out, int out_size, void* d_ws, size_t ws_size,
                              hipStream_t stream) {
    const float* hidden = (const float*)d_in[0];
    const int*   amask  = (const int*)d_in[1];
    const float* Wq  = (const float*)d_in[2];
    const float* Wk  = (const float*)d_in[3];
    const float* Wv  = (const float*)d_in[4];
    const float* Wo  = (const float*)d_in[5];
    const float* l1g = (const float*)d_in[6];
    const float* l1b = (const float*)d_in[7];
    const float* W1  = (const float*)d_in[8];
    const float* b1  = (const float*)d_in[9];
    const float* W2  = (const float*)d_in[10];
    const float* b2  = (const float*)d_in[11];
    const float* l2g = (const float*)d_in[12];
    const float* l2b = (const float*)d_in[13];

    const int M = 8192;
    const size_t MB = 1048576;
    char* ws = (char*)d_ws;
    ushort* xa    = (ushort*)(ws);
    ushort* qkvb  = (ushort*)(ws + 16 * MB);
    ushort* Wqkvt = (ushort*)(ws + 64 * MB);
    ushort* Wot   = (ushort*)(ws + 70 * MB);
    ushort* W1t   = (ushort*)(ws);
    ushort* W2t   = (ushort*)(ws + 8 * MB);
    ushort* yb    = (ushort*)(ws + 16 * MB);
    ushort* hbc   = (ushort*)(ws + 32 * MB);
    float*  x2    = (float*)d_out;

    cvt_t_kernel<<<dim3(32, 32), 256, 0, stream>>>(Wq, Wqkvt, 1024, 1024);
    cvt_t_kernel<<<dim3(32, 32), 256, 0, stream>>>(Wk, Wqkvt + (size_t)1024 * 1024, 1024, 1024);
    cvt_t_kernel<<<dim3(32, 32), 256, 0, stream>>>(Wv, Wqkvt + (size_t)2048 * 1024, 1024, 1024);
    cvt_t_kernel<<<dim3(32, 32), 256, 0, stream>>>(Wo, Wot, 1024, 1024);

    ln_kernel<<<M, 256, 0, stream>>>(hidden, l1g, l1b, xa);
    gemm256_kernel<false, false><<<dim3(12, 32), 512, 0, stream>>>(
        xa, Wqkvt, nullptr, qkvb, M, 3072, 1024);
    attn_kernel<<<dim3(16, 64), 256, 0, stream>>>(
        qkvb, qkvb + 1024, qkvb + 2048, amask, xa, 3072);
    gemm_bt_kernel<64, false, false, true, true><<<dim3(16, 64), 256, 0, stream>>>(
        xa, Wot, nullptr, hidden, x2, M, 1024, 1024);

    cvt_t_kernel<<<dim3(128, 32), 256, 0, stream>>>(W1, W1t, 1024, 4096);
    cvt_t_kernel<<<dim3(32, 128), 256, 0, stream>>>(W2, W2t, 4096, 1024);

    ln_kernel<<<M, 256, 0, stream>>>(x2, l2g, l2b, yb);
    for (int mc = 0; mc < 2; ++mc) {
        const size_t off = (size_t)mc * 4096 * 1024;
        gemm256_kernel<true, true><<<dim3(16, 16), 512, 0, stream>>>(
            yb + off, W1t, b1, hbc, 4096, 4096, 1024);
        gemm_bt_kernel<64, true, false, true, true><<<dim3(16, 32), 256, 0, stream>>>(
            hbc, W2t, b2, x2 + off, (void*)(x2 + off), 4096, 1024, 4096);
    }
}